// Round 3
// baseline (2087.570 us; speedup 1.0000x reference)
//
#include <hip/hip_runtime.h>
#include <hip/hip_bf16.h>

#define NBAND 7
#define BBATCH 16
#define TSEQ 512
#define DMODEL 128
#define MBAND (BBATCH * TSEQ)               // 8192 rows per band
#define BANDE ((size_t)MBAND * DMODEL)      // 1,048,576 elements per band

// ---------------------------------------------------------------------------
// Generic multi-K-part GEMM:  C = epilogue( alpha * (sum_p A_p @ W_p) + bias )
//   A_p: M x partK (row stride partK), W_p: partK x N (row stride N)
// Tile 64x64, 256 threads, 4x4 per thread, TILE_K = 32.
// ---------------------------------------------------------------------------
struct GArgs {
  const float* A[6];
  const float* W[6];
  int nparts;
  int partK;
  int M, N;
  const float* bias;   // length N (may be null)
  float alpha;
  int op;              // 0 store, 1 gelu, 2 sigmoid, 3 resid+, 4 resid+sig(v)*extra, 5 resid+extra*v
  const float* resid;
  const float* extra;
  float* outF;
};

__global__ __launch_bounds__(256) void gemm_kernel(GArgs g) {
  __shared__ float As[32][65];
  __shared__ float Ws[32][64];
  const int m0 = blockIdx.x * 64;
  const int n0 = blockIdx.y * 64;
  const int tid = threadIdx.x;
  const int tx = tid & 15, ty = tid >> 4;
  float acc[4][4] = {{0.f}};

  for (int p = 0; p < g.nparts; ++p) {
    const float* A = g.A[p];
    const float* W = g.W[p];
    for (int k0 = 0; k0 < g.partK; k0 += 32) {
      #pragma unroll
      for (int i = 0; i < 8; ++i) {
        int f = tid + i * 256;            // 2048 elements: 64 rows x 32 k
        int m = f >> 5, k = f & 31;
        As[k][m] = A[(size_t)(m0 + m) * g.partK + (k0 + k)];
      }
      #pragma unroll
      for (int i = 0; i < 8; ++i) {
        int f = tid + i * 256;            // 2048 elements: 32 k x 64 n
        int k = f >> 6, n = f & 63;
        Ws[k][n] = W[(size_t)(k0 + k) * g.N + (n0 + n)];
      }
      __syncthreads();
      #pragma unroll
      for (int kk = 0; kk < 32; ++kk) {
        float a[4], b[4];
        #pragma unroll
        for (int i = 0; i < 4; ++i) a[i] = As[kk][ty * 4 + i];
        #pragma unroll
        for (int j = 0; j < 4; ++j) b[j] = Ws[kk][tx * 4 + j];
        #pragma unroll
        for (int i = 0; i < 4; ++i)
          #pragma unroll
          for (int j = 0; j < 4; ++j)
            acc[i][j] += a[i] * b[j];
      }
      __syncthreads();
    }
  }

  #pragma unroll
  for (int i = 0; i < 4; ++i) {
    int m = m0 + ty * 4 + i;
    #pragma unroll
    for (int j = 0; j < 4; ++j) {
      int n = n0 + tx * 4 + j;
      float v = acc[i][j] * g.alpha;
      if (g.bias) v += g.bias[n];
      size_t idx = (size_t)m * g.N + n;
      switch (g.op) {
        case 0: g.outF[idx] = v; break;
        case 1: g.outF[idx] = 0.5f * v * (1.f + erff(v * 0.70710678118654752f)); break;
        case 2: g.outF[idx] = 1.f / (1.f + __expf(-v)); break;
        case 3: g.outF[idx] = g.resid[idx] + v; break;
        case 4: {
          float gate = 1.f / (1.f + __expf(-v));
          g.outF[idx] = g.resid[idx] + gate * g.extra[idx];   // fp32 store
        } break;
        case 5: {
          float gm = g.extra ? g.extra[idx] : 1.f;
          g.outF[idx] = g.resid[idx] + gm * v;
        } break;
      }
    }
  }
}

// ---------------------------------------------------------------------------
// Flash-style causal attention for ONE band, fp32. H=2, HD=64, T=512.
// grid.x = BBATCH*2 (bh) * 8 (q-tiles of 64 rows). 256 threads.
// thread t: local q-row r = t>>2 (0..63), dim quarter c = t&3 (16 dims).
// ---------------------------------------------------------------------------
__global__ __launch_bounds__(256) void attn_kernel(const float* __restrict__ q,
                                                   const float* __restrict__ k,
                                                   const float* __restrict__ v,
                                                   float* __restrict__ o) {
  const int qt = blockIdx.x & 7;
  const int bh = blockIdx.x >> 3;
  const int h  = bh & 1;
  const int b  = bh >> 1;                       // 0..15
  const size_t rowbase = (size_t)b * TSEQ;

  const int tid = threadIdx.x;
  const int r = tid >> 2;
  const int c = tid & 3;
  const int qrow = qt * 64 + r;

  __shared__ float Kt[64][64];
  __shared__ float Vt[64][64];

  float qreg[16];
  {
    const float* qp = q + (rowbase + qrow) * DMODEL + h * 64 + c * 16;
    #pragma unroll
    for (int i = 0; i < 16; ++i) qreg[i] = qp[i] * 0.125f;  // 1/sqrt(64)
  }

  float m = -1e30f, l = 0.f;
  float outv[16];
  #pragma unroll
  for (int i = 0; i < 16; ++i) outv[i] = 0.f;

  for (int kt = 0; kt <= qt; ++kt) {
    __syncthreads();
    #pragma unroll
    for (int i = 0; i < 16; ++i) {
      int f = tid + i * 256;                    // 4096 = 64x64
      int s_ = f >> 6, dd = f & 63;
      size_t gidx = (rowbase + kt * 64 + s_) * DMODEL + h * 64 + dd;
      Kt[s_][dd] = k[gidx];
      Vt[s_][dd] = v[gidx];
    }
    __syncthreads();

    for (int ch = 0; ch < 4; ++ch) {
      float sc[16];
      #pragma unroll
      for (int j = 0; j < 16; ++j) {
        int key = ch * 16 + j;
        float p = 0.f;
        #pragma unroll
        for (int i = 0; i < 16; ++i) p += qreg[i] * Kt[key][c * 16 + i];
        p += __shfl_xor(p, 1);
        p += __shfl_xor(p, 2);
        int gkey = kt * 64 + key;
        sc[j] = (gkey <= qrow) ? p : -1e30f;
      }
      float mx = m;
      #pragma unroll
      for (int j = 0; j < 16; ++j) mx = fmaxf(mx, sc[j]);
      float alpha = __expf(m - mx);
      l *= alpha;
      #pragma unroll
      for (int i = 0; i < 16; ++i) outv[i] *= alpha;
      #pragma unroll
      for (int j = 0; j < 16; ++j) {
        float p = __expf(sc[j] - mx);
        l += p;
        int key = ch * 16 + j;
        #pragma unroll
        for (int i = 0; i < 16; ++i) outv[i] += p * Vt[key][c * 16 + i];
      }
      m = mx;
    }
  }

  float inv = 1.f / l;
  float* op = o + (rowbase + qrow) * DMODEL + h * 64 + c * 16;
  #pragma unroll
  for (int i = 0; i < 16; ++i) op[i] = outv[i] * inv;
}

// ---------------------------------------------------------------------------
// LayerNorm over last dim (128) for one band. Block = 4 rows x 64 lanes.
// ---------------------------------------------------------------------------
__global__ __launch_bounds__(256) void ln_kernel(const float* __restrict__ x,
                                                 float* __restrict__ xn,
                                                 const float* __restrict__ ls,
                                                 const float* __restrict__ lb) {
  const int tid = threadIdx.x;
  const int rr = tid >> 6, lane = tid & 63;
  const size_t row = (size_t)blockIdx.x * 4 + rr;
  const float* xp = x + row * DMODEL;
  float a = xp[lane], b = xp[lane + 64];
  float s = a + b;
  #pragma unroll
  for (int off = 32; off; off >>= 1) s += __shfl_xor(s, off);
  float mean = s * (1.f / 128.f);
  float da = a - mean, db = b - mean;
  float vs = da * da + db * db;
  #pragma unroll
  for (int off = 32; off; off >>= 1) vs += __shfl_xor(vs, off);
  float rstd = rsqrtf(vs * (1.f / 128.f) + 1e-5f);
  float* op = xn + row * DMODEL;
  op[lane]      = da * rstd * ls[lane]      + lb[lane];
  op[lane + 64] = db * rstd * ls[lane + 64] + lb[lane + 64];
}

__global__ void bias6_kernel(const float* __restrict__ br_b, float* __restrict__ out) {
  int d = threadIdx.x;
  float s = 0.f;
  #pragma unroll
  for (int j = 0; j < 6; ++j) s += br_b[j * 128 + d];
  out[d] = s * (1.f / 6.f);
}

// ---------------------------------------------------------------------------
extern "C" void kernel_launch(void* const* d_in, const int* in_sizes, int n_in,
                              void* d_out, int out_size, void* d_ws, size_t ws_size,
                              hipStream_t stream) {
  // Inputs arrive in setup_inputs() dict order; keep a signature-order
  // fallback keyed on in_sizes[2] (dict: Wk=114688, signature: bq=896).
  bool dict = (in_sizes[2] != 896);
  const float* bands = (const float*)d_in[0];
  const float* Wq = (const float*)d_in[1];
  const float *Wk, *Wv, *Wo, *bq, *bk, *bv, *bo;
  if (dict) {
    Wk = (const float*)d_in[2]; Wv = (const float*)d_in[3]; Wo = (const float*)d_in[4];
    bq = (const float*)d_in[5]; bk = (const float*)d_in[6];
    bv = (const float*)d_in[7]; bo = (const float*)d_in[8];
  } else {
    bq = (const float*)d_in[2]; Wk = (const float*)d_in[3]; bk = (const float*)d_in[4];
    Wv = (const float*)d_in[5]; bv = (const float*)d_in[6];
    Wo = (const float*)d_in[7]; bo = (const float*)d_in[8];
  }
  const float* g_ls = (const float*)d_in[9];
  const float* g_lb = (const float*)d_in[10];
  const float* g_w1 = (const float*)d_in[11];
  const float* g_b1 = (const float*)d_in[12];
  const float* g_w2 = (const float*)d_in[13];
  const float* g_b2 = (const float*)d_in[14];
  const float* g_wg = (const float*)d_in[15];
  const float* g_bg = (const float*)d_in[16];
  const float* h_ls = (const float*)d_in[17];
  const float* h_lb = (const float*)d_in[18];
  const float* h_w1 = (const float*)d_in[19];
  const float* h_b1 = (const float*)d_in[20];
  const float* h_w2 = (const float*)d_in[21];
  const float* h_b2 = (const float*)d_in[22];
  const float* r_ls = (const float*)d_in[23];
  const float* r_lb = (const float*)d_in[24];
  const float* r_w1 = (const float*)d_in[25];
  const float* r_b1 = (const float*)d_in[26];
  const float* r_w2 = (const float*)d_in[27];
  const float* r_b2 = (const float*)d_in[28];
  const float* wp_w = (const float*)d_in[29];
  const float* wp_b = (const float*)d_in[30];
  const float* wg_w = (const float*)d_in[31];
  const float* wg_b = (const float*)d_in[32];
  const float* br_w = (const float*)d_in[33];
  const float* br_b = (const float*)d_in[34];
  const float* bg_w = (const float*)d_in[35];
  const float* bg_b = (const float*)d_in[36];
  float* out = (float*)d_out;   // reference output dtype is float32

  // ---- Compact workspace: 15 BANDE + 128 floats ~= 63 MB ----
  float* ws = (float*)d_ws;
  float* yb   = ws;                         // 7 BANDE
  float* sq   = yb + 7 * BANDE;             // 1 BANDE
  float* sk   = sq + BANDE;                 // 1 BANDE
  float* sv   = sk + BANDE;                 // 1 BANDE
  float* so   = sv + BANDE;                 // 1 BANDE
  float* shid = so + BANDE;                 // 4 BANDE
  float* bbias = shid + 4 * BANDE;          // 128

  auto G = [&](GArgs& g) {
    dim3 grid(g.M / 64, g.N / 64);
    gemm_kernel<<<grid, dim3(256), 0, stream>>>(g);
  };

  // Per-band parameter tables
  const int hN[7] = {256, 256, 256, 384, 384, 512, 512};
  const float* lsP[7] = {g_ls, g_ls + 128, g_ls + 256, h_ls, h_ls + 128, r_ls, r_ls + 128};
  const float* lbP[7] = {g_lb, g_lb + 128, g_lb + 256, h_lb, h_lb + 128, r_lb, r_lb + 128};
  const float* w1p[7] = {g_w1, g_w1 + 32768, g_w1 + 65536,
                         h_w1, h_w1 + 49152, r_w1, r_w1 + 65536};
  const float* b1p[7] = {g_b1, g_b1 + 256, g_b1 + 512,
                         h_b1, h_b1 + 384, r_b1, r_b1 + 512};
  const float* w2p[7] = {g_w2, g_w2 + 32768, g_w2 + 65536,
                         h_w2, h_w2 + 49152, r_w2, r_w2 + 65536};
  const float* b2p[7] = {g_b2, g_b2 + 128, g_b2 + 256,
                         h_b2, h_b2 + 128, r_b2, r_b2 + 128};

  // ================= per-band pipeline =================
  for (int n = 0; n < NBAND; ++n) {
    const float* bn = bands + (size_t)n * BANDE;

    // 1. QKV projections
    const float* W3[3] = {Wq + n * 16384, Wk + n * 16384, Wv + n * 16384};
    const float* b3[3] = {bq + n * 128, bk + n * 128, bv + n * 128};
    float* o3[3] = {sq, sk, sv};
    for (int w = 0; w < 3; ++w) {
      GArgs g{};
      g.A[0] = bn; g.W[0] = W3[w];
      g.nparts = 1; g.partK = 128; g.M = MBAND; g.N = 128;
      g.bias = b3[w]; g.alpha = 1.f; g.op = 0; g.outF = o3[w];
      G(g);
    }

    // 2. causal attention (q,k,v dead afterwards)
    attn_kernel<<<dim3(BBATCH * 2 * 8), dim3(256), 0, stream>>>(sq, sk, sv, so);

    // 3. x = bands + o @ Wo + bo   (x -> sq)
    {
      GArgs g{};
      g.A[0] = so; g.W[0] = Wo + n * 16384;
      g.nparts = 1; g.partK = 128; g.M = MBAND; g.N = 128;
      g.bias = bo + n * 128; g.alpha = 1.f; g.op = 3;
      g.resid = bn; g.outF = sq;
      G(g);
    }

    // 4. xn = LN(x)  (xn -> sk)
    ln_kernel<<<dim3(MBAND / 4), dim3(256), 0, stream>>>(sq, sk, lsP[n], lbP[n]);

    // 5. geo gate = sigmoid(x @ g_wg + g_bg)  (gate -> sv)
    if (n < 3) {
      GArgs g{};
      g.A[0] = sq; g.W[0] = g_wg + n * 16384;
      g.nparts = 1; g.partK = 128; g.M = MBAND; g.N = 128;
      g.bias = g_bg + n * 128; g.alpha = 1.f; g.op = 2;
      g.outF = sv;
      G(g);
    }

    // 6. hid = gelu(xn @ w1 + b1)
    {
      GArgs g{};
      g.A[0] = sk; g.W[0] = w1p[n];
      g.nparts = 1; g.partK = 128; g.M = MBAND; g.N = hN[n];
      g.bias = b1p[n]; g.alpha = 1.f; g.op = 1;
      g.outF = shid;
      G(g);
    }

    // 7. y = x + [gate] * (hid @ w2 + b2)
    {
      GArgs g{};
      g.A[0] = shid; g.W[0] = w2p[n];
      g.nparts = 1; g.partK = hN[n]; g.M = MBAND; g.N = 128;
      g.bias = b2p[n]; g.alpha = 1.f; g.op = 5;
      g.resid = sq;
      g.extra = (n < 3) ? sv : nullptr;
      g.outF = yb + (size_t)n * BANDE;
      G(g);
    }
  }

  // ================= cross-band mixing =================
  const int outb[6] = {0, 1, 2, 4, 5, 6};
  for (int s = 0; s < 6; ++s) {
    int t = outb[s];
    int i = (t < 3) ? t : 6 - t;
    int src = 6 - t;

    // info[t] = y[src] @ wp_w[i] + wp_b[i]   (-> sq)
    {
      GArgs g{};
      g.A[0] = yb + (size_t)src * BANDE; g.W[0] = wp_w + i * 16384;
      g.nparts = 1; g.partK = 128; g.M = MBAND; g.N = 128;
      g.bias = wp_b + i * 128; g.alpha = 1.f; g.op = 0;
      g.outF = sq;
      G(g);
    }
    // out[t] = y[t] + sigmoid([y[t], info] @ wg_w[i] + wg_b[i]) * info
    {
      GArgs g{};
      g.A[0] = yb + (size_t)t * BANDE; g.W[0] = wg_w + i * 32768;
      g.A[1] = sq;                      g.W[1] = wg_w + i * 32768 + 16384;
      g.nparts = 2; g.partK = 128; g.M = MBAND; g.N = 128;
      g.bias = wg_b + i * 128; g.alpha = 1.f; g.op = 4;
      g.resid = yb + (size_t)t * BANDE;
      g.extra = sq;
      g.outF = out + (size_t)t * BANDE;
      G(g);
    }
  }

  // band 3: bridge = (sum_j y[bl_j] @ br_w[j] + sum(br_b)) / 6   (-> sk)
  bias6_kernel<<<dim3(1), dim3(128), 0, stream>>>(br_b, bbias);
  {
    GArgs g{};
    const int bl[6] = {0, 1, 2, 4, 5, 6};
    for (int j = 0; j < 6; ++j) {
      g.A[j] = yb + (size_t)bl[j] * BANDE;
      g.W[j] = br_w + j * 16384;
    }
    g.nparts = 6; g.partK = 128; g.M = MBAND; g.N = 128;
    g.bias = bbias; g.alpha = 1.f / 6.f; g.op = 0; g.outF = sk;
    G(g);
  }
  {
    GArgs g{};
    g.A[0] = yb + 3 * BANDE; g.W[0] = bg_w;
    g.A[1] = sk;             g.W[1] = bg_w + 16384;
    g.nparts = 2; g.partK = 128; g.M = MBAND; g.N = 128;
    g.bias = bg_b; g.alpha = 1.f; g.op = 4;
    g.resid = yb + 3 * BANDE;
    g.extra = sk;
    g.outF = out + 3 * BANDE;
    G(g);
  }
}

// Round 4
// 1062.572 us; speedup vs baseline: 1.9646x; 1.9646x over previous
//
#include <hip/hip_runtime.h>
#include <hip/hip_bf16.h>

#define NBAND 7
#define BBATCH 16
#define TSEQ 512
#define DMODEL 128
#define MBAND (BBATCH * TSEQ)               // 8192 rows per band
#define BANDE ((size_t)MBAND * DMODEL)      // 1,048,576 elements per band

// ---------------------------------------------------------------------------
// Batched GEMM over blockIdx.z:  C_z = epi( alpha*(A_z@W_z [+ A2_z@W2_z]) + b_z )
// M fixed 8192; 64x64 tile, 256 threads, 4x4/thread, TILE_K=32.
// Per-z pointer = base + off[z]; null base disables the feature.
// ---------------------------------------------------------------------------
struct PArgs {
  const float *A, *W, *bias, *A2, *W2, *resid, *extra;
  float* O;
  size_t Aoff[8], Woff[8], boff[8], A2off[8], W2off[8], roff[8], eoff[8], Ooff[8];
  int K, N, op;     // op: 0 store 1 gelu 2 sigmoid 3 resid+ 4 resid+sig(v)*extra 5 resid+extra*v
  float alpha;
};

__device__ __forceinline__ void mm_tile(const float* __restrict__ A,
                                        const float* __restrict__ W,
                                        int K, int N, int m0, int n0, int tid,
                                        float (*As)[65], float (*Ws)[64],
                                        float acc[4][4]) {
  const int tx = tid & 15, ty = tid >> 4;
  for (int k0 = 0; k0 < K; k0 += 32) {
    #pragma unroll
    for (int i = 0; i < 8; ++i) {
      int f = tid + i * 256;            // 64 rows x 32 k
      int m = f >> 5, k = f & 31;
      As[k][m] = A[(size_t)(m0 + m) * K + (k0 + k)];
    }
    #pragma unroll
    for (int i = 0; i < 8; ++i) {
      int f = tid + i * 256;            // 32 k x 64 n
      int k = f >> 6, n = f & 63;
      Ws[k][n] = W[(size_t)(k0 + k) * N + (n0 + n)];
    }
    __syncthreads();
    #pragma unroll
    for (int kk = 0; kk < 32; ++kk) {
      float a[4], b[4];
      #pragma unroll
      for (int i = 0; i < 4; ++i) a[i] = As[kk][ty * 4 + i];
      #pragma unroll
      for (int j = 0; j < 4; ++j) b[j] = Ws[kk][tx * 4 + j];
      #pragma unroll
      for (int i = 0; i < 4; ++i)
        #pragma unroll
        for (int j = 0; j < 4; ++j)
          acc[i][j] += a[i] * b[j];
    }
    __syncthreads();
  }
}

__global__ __launch_bounds__(256) void gemm_b(PArgs p) {
  __shared__ float As[32][65];
  __shared__ float Ws[32][64];
  const int z = blockIdx.z;
  const int m0 = blockIdx.x * 64, n0 = blockIdx.y * 64;
  const int tid = threadIdx.x;
  const int tx = tid & 15, ty = tid >> 4;
  float acc[4][4] = {{0.f}};

  mm_tile(p.A + p.Aoff[z], p.W + p.Woff[z], p.K, p.N, m0, n0, tid, As, Ws, acc);
  if (p.A2)
    mm_tile(p.A2 + p.A2off[z], p.W2 + p.W2off[z], p.K, p.N, m0, n0, tid, As, Ws, acc);

  const float* bias  = p.bias  ? p.bias  + p.boff[z] : nullptr;
  const float* resid = p.resid ? p.resid + p.roff[z] : nullptr;
  const float* extra = p.extra ? p.extra + p.eoff[z] : nullptr;
  float* O = p.O + p.Ooff[z];

  #pragma unroll
  for (int i = 0; i < 4; ++i) {
    int m = m0 + ty * 4 + i;
    #pragma unroll
    for (int j = 0; j < 4; ++j) {
      int n = n0 + tx * 4 + j;
      float v = acc[i][j] * p.alpha;
      if (bias) v += bias[n];
      size_t idx = (size_t)m * p.N + n;
      switch (p.op) {
        case 0: O[idx] = v; break;
        case 1: O[idx] = 0.5f * v * (1.f + erff(v * 0.70710678118654752f)); break;
        case 2: O[idx] = 1.f / (1.f + __expf(-v)); break;
        case 3: O[idx] = resid[idx] + v; break;
        case 4: {
          float gate = 1.f / (1.f + __expf(-v));
          O[idx] = resid[idx] + gate * extra[idx];
        } break;
        case 5: {
          float gm = extra ? extra[idx] : 1.f;
          O[idx] = resid[idx] + gm * v;
        } break;
      }
    }
  }
}

// 6-part bridge: O = (sum_j y[bl_j] @ br_w[j]) / 6 + bbias   (bbias = sum(br_b)/6)
__global__ __launch_bounds__(256) void bridge_kernel(const float* __restrict__ yb,
                                                     const float* __restrict__ br_w,
                                                     const float* __restrict__ bbias,
                                                     float* __restrict__ O) {
  __shared__ float As[32][65];
  __shared__ float Ws[32][64];
  const int m0 = blockIdx.x * 64, n0 = blockIdx.y * 64;
  const int tid = threadIdx.x;
  const int tx = tid & 15, ty = tid >> 4;
  float acc[4][4] = {{0.f}};
  const int bl[6] = {0, 1, 2, 4, 5, 6};
  for (int j = 0; j < 6; ++j)
    mm_tile(yb + (size_t)bl[j] * BANDE, br_w + j * 16384, 128, 128, m0, n0, tid, As, Ws, acc);
  #pragma unroll
  for (int i = 0; i < 4; ++i) {
    int m = m0 + ty * 4 + i;
    #pragma unroll
    for (int j = 0; j < 4; ++j) {
      int n = n0 + tx * 4 + j;
      O[(size_t)m * 128 + n] = acc[i][j] * (1.f / 6.f) + bbias[n];
    }
  }
}

// ---------------------------------------------------------------------------
// Flash-style causal attention, fp32. H=2, HD=64, T=512, multi-band.
// grid.x = nbands*256; block: band = bx>>8, qt = bx&7, bh = (bx>>3)&31.
// ---------------------------------------------------------------------------
__global__ __launch_bounds__(256) void attn_kernel(const float* __restrict__ q,
                                                   const float* __restrict__ k,
                                                   const float* __restrict__ v,
                                                   float* __restrict__ o) {
  const int band = blockIdx.x >> 8;
  const int rest = blockIdx.x & 255;
  const int qt = rest & 7;
  const int bh = rest >> 3;
  const int h  = bh & 1;
  const int b  = bh >> 1;
  const size_t rowbase = ((size_t)band * BBATCH + b) * TSEQ;

  const int tid = threadIdx.x;
  const int r = tid >> 2;
  const int c = tid & 3;
  const int qrow = qt * 64 + r;

  __shared__ float Kt[64][64];
  __shared__ float Vt[64][64];

  float qreg[16];
  {
    const float* qp = q + (rowbase + qrow) * DMODEL + h * 64 + c * 16;
    #pragma unroll
    for (int i = 0; i < 16; ++i) qreg[i] = qp[i] * 0.125f;  // 1/sqrt(64)
  }

  float m = -1e30f, l = 0.f;
  float outv[16];
  #pragma unroll
  for (int i = 0; i < 16; ++i) outv[i] = 0.f;

  for (int kt = 0; kt <= qt; ++kt) {
    __syncthreads();
    #pragma unroll
    for (int i = 0; i < 16; ++i) {
      int f = tid + i * 256;                    // 4096 = 64x64
      int s_ = f >> 6, dd = f & 63;
      size_t gidx = (rowbase + kt * 64 + s_) * DMODEL + h * 64 + dd;
      Kt[s_][dd] = k[gidx];
      Vt[s_][dd] = v[gidx];
    }
    __syncthreads();

    for (int ch = 0; ch < 4; ++ch) {
      float sc[16];
      #pragma unroll
      for (int j = 0; j < 16; ++j) {
        int key = ch * 16 + j;
        float p = 0.f;
        #pragma unroll
        for (int i = 0; i < 16; ++i) p += qreg[i] * Kt[key][c * 16 + i];
        p += __shfl_xor(p, 1);
        p += __shfl_xor(p, 2);
        int gkey = kt * 64 + key;
        sc[j] = (gkey <= qrow) ? p : -1e30f;
      }
      float mx = m;
      #pragma unroll
      for (int j = 0; j < 16; ++j) mx = fmaxf(mx, sc[j]);
      float alpha = __expf(m - mx);
      l *= alpha;
      #pragma unroll
      for (int i = 0; i < 16; ++i) outv[i] *= alpha;
      #pragma unroll
      for (int j = 0; j < 16; ++j) {
        float p = __expf(sc[j] - mx);
        l += p;
        int key = ch * 16 + j;
        #pragma unroll
        for (int i = 0; i < 16; ++i) outv[i] += p * Vt[key][c * 16 + i];
      }
      m = mx;
    }
  }

  float inv = 1.f / l;
  float* op = o + (rowbase + qrow) * DMODEL + h * 64 + c * 16;
  #pragma unroll
  for (int i = 0; i < 16; ++i) op[i] = outv[i] * inv;
}

// ---------------------------------------------------------------------------
// LayerNorm over last dim (128), band-indexed scale/bias (band = row>>13).
// ---------------------------------------------------------------------------
struct LNA {
  const float* x;
  float* xn;
  const float* ls[7];
  const float* lb[7];
};

__global__ __launch_bounds__(256) void ln_kernel(LNA p) {
  const int tid = threadIdx.x;
  const int rr = tid >> 6, lane = tid & 63;
  const size_t row = (size_t)blockIdx.x * 4 + rr;
  const float* xp = p.x + row * DMODEL;
  float a = xp[lane], b = xp[lane + 64];
  float s = a + b;
  #pragma unroll
  for (int off = 32; off; off >>= 1) s += __shfl_xor(s, off);
  float mean = s * (1.f / 128.f);
  float da = a - mean, db = b - mean;
  float vs = da * da + db * db;
  #pragma unroll
  for (int off = 32; off; off >>= 1) vs += __shfl_xor(vs, off);
  float rstd = rsqrtf(vs * (1.f / 128.f) + 1e-5f);
  int band = (int)(row >> 13);
  const float* ls = p.ls[band];
  const float* lb = p.lb[band];
  float* op = p.xn + row * DMODEL;
  op[lane]      = da * rstd * ls[lane]      + lb[lane];
  op[lane + 64] = db * rstd * ls[lane + 64] + lb[lane + 64];
}

__global__ void bias6_kernel(const float* __restrict__ br_b, float* __restrict__ out) {
  int d = threadIdx.x;
  float s = 0.f;
  #pragma unroll
  for (int j = 0; j < 6; ++j) s += br_b[j * 128 + d];
  out[d] = s * (1.f / 6.f);
}

// ---------------------------------------------------------------------------
extern "C" void kernel_launch(void* const* d_in, const int* in_sizes, int n_in,
                              void* d_out, int out_size, void* d_ws, size_t ws_size,
                              hipStream_t stream) {
  bool dict = (in_sizes[2] != 896);
  const float* bands = (const float*)d_in[0];
  const float* Wq = (const float*)d_in[1];
  const float *Wk, *Wv, *Wo, *bq, *bk, *bv, *bo;
  if (dict) {
    Wk = (const float*)d_in[2]; Wv = (const float*)d_in[3]; Wo = (const float*)d_in[4];
    bq = (const float*)d_in[5]; bk = (const float*)d_in[6];
    bv = (const float*)d_in[7]; bo = (const float*)d_in[8];
  } else {
    bq = (const float*)d_in[2]; Wk = (const float*)d_in[3]; bk = (const float*)d_in[4];
    Wv = (const float*)d_in[5]; bv = (const float*)d_in[6];
    Wo = (const float*)d_in[7]; bo = (const float*)d_in[8];
  }
  const float* g_ls = (const float*)d_in[9];
  const float* g_lb = (const float*)d_in[10];
  const float* g_w1 = (const float*)d_in[11];
  const float* g_b1 = (const float*)d_in[12];
  const float* g_w2 = (const float*)d_in[13];
  const float* g_b2 = (const float*)d_in[14];
  const float* g_wg = (const float*)d_in[15];
  const float* g_bg = (const float*)d_in[16];
  const float* h_ls = (const float*)d_in[17];
  const float* h_lb = (const float*)d_in[18];
  const float* h_w1 = (const float*)d_in[19];
  const float* h_b1 = (const float*)d_in[20];
  const float* h_w2 = (const float*)d_in[21];
  const float* h_b2 = (const float*)d_in[22];
  const float* r_ls = (const float*)d_in[23];
  const float* r_lb = (const float*)d_in[24];
  const float* r_w1 = (const float*)d_in[25];
  const float* r_b1 = (const float*)d_in[26];
  const float* r_w2 = (const float*)d_in[27];
  const float* r_b2 = (const float*)d_in[28];
  const float* wp_w = (const float*)d_in[29];
  const float* wp_b = (const float*)d_in[30];
  const float* wg_w = (const float*)d_in[31];
  const float* wg_b = (const float*)d_in[32];
  const float* br_w = (const float*)d_in[33];
  const float* br_b = (const float*)d_in[34];
  const float* bg_w = (const float*)d_in[35];
  const float* bg_b = (const float*)d_in[36];
  float* out = (float*)d_out;

  const int hN[7] = {256, 256, 256, 384, 384, 512, 512};
  const float* lsP[7] = {g_ls, g_ls + 128, g_ls + 256, h_ls, h_ls + 128, r_ls, r_ls + 128};
  const float* lbP[7] = {g_lb, g_lb + 128, g_lb + 256, h_lb, h_lb + 128, r_lb, r_lb + 128};
  const float* w1p[7] = {g_w1, g_w1 + 32768, g_w1 + 65536,
                         h_w1, h_w1 + 49152, r_w1, r_w1 + 65536};
  const float* b1p[7] = {g_b1, g_b1 + 256, g_b1 + 512,
                         h_b1, h_b1 + 384, r_b1, r_b1 + 512};
  const float* w2p[7] = {g_w2, g_w2 + 32768, g_w2 + 65536,
                         h_w2, h_w2 + 49152, r_w2, r_w2 + 65536};
  const float* b2p[7] = {g_b2, g_b2 + 128, g_b2 + 256,
                         h_b2, h_b2 + 128, r_b2, r_b2 + 128};

  auto LP = [&](PArgs& p, int Z) {
    dim3 grid(MBAND / 64, p.N / 64, Z);
    gemm_b<<<grid, dim3(256), 0, stream>>>(p);
  };

  float* ws = (float*)d_ws;
  const size_t needFast = (36 * BANDE + 256) * sizeof(float);   // ~151 MB

  if (ws_size >= needFast) {
    // =================== FAST PATH: all bands batched ===================
    float* qb  = ws;                 // 7 BANDE   (later: x)
    float* kb  = qb + 7 * BANDE;     // 7 BANDE   (later: xn)
    float* vb  = kb + 7 * BANDE;     // 7 BANDE   (later: gate, 3 used)
    float* ob  = vb + 7 * BANDE;     // 7 BANDE   (later: y)
    float* hid = ob + 7 * BANDE;     // 8 BANDE   (later: info 6 + bridge 1)
    float* bbias = hid + 8 * BANDE;  // 128
    float* xb = qb;
    float* xnb = kb;
    float* gateb = vb;
    float* yb = ob;
    float* info = hid;
    float* bridge = hid + 6 * BANDE;

    // 1-3. Q/K/V projections, Z=7 each
    const float* Wqkv[3] = {Wq, Wk, Wv};
    const float* bqkv[3] = {bq, bk, bv};
    float* oqkv[3] = {qb, kb, vb};
    for (int w = 0; w < 3; ++w) {
      PArgs p{};
      p.A = bands; p.W = Wqkv[w]; p.bias = bqkv[w]; p.O = oqkv[w];
      for (int z = 0; z < 7; ++z) {
        p.Aoff[z] = z * BANDE; p.Woff[z] = (size_t)z * 16384;
        p.boff[z] = (size_t)z * 128; p.Ooff[z] = z * BANDE;
      }
      p.K = 128; p.N = 128; p.op = 0; p.alpha = 1.f;
      LP(p, 7);
    }

    // 4. attention, all bands
    attn_kernel<<<dim3(NBAND * 256), dim3(256), 0, stream>>>(qb, kb, vb, ob);

    // 5. x = bands + o @ Wo + bo  (-> qb region)
    {
      PArgs p{};
      p.A = ob; p.W = Wo; p.bias = bo; p.resid = bands; p.O = xb;
      for (int z = 0; z < 7; ++z) {
        p.Aoff[z] = z * BANDE; p.Woff[z] = (size_t)z * 16384;
        p.boff[z] = (size_t)z * 128; p.roff[z] = z * BANDE; p.Ooff[z] = z * BANDE;
      }
      p.K = 128; p.N = 128; p.op = 3; p.alpha = 1.f;
      LP(p, 7);
    }

    // 6. LN all bands
    {
      LNA p{};
      p.x = xb; p.xn = xnb;
      for (int n = 0; n < 7; ++n) { p.ls[n] = lsP[n]; p.lb[n] = lbP[n]; }
      ln_kernel<<<dim3(NBAND * MBAND / 4), dim3(256), 0, stream>>>(p);
    }

    // 7. geo gates, Z=3
    {
      PArgs p{};
      p.A = xb; p.W = g_wg; p.bias = g_bg; p.O = gateb;
      for (int z = 0; z < 3; ++z) {
        p.Aoff[z] = z * BANDE; p.Woff[z] = (size_t)z * 16384;
        p.boff[z] = (size_t)z * 128; p.Ooff[z] = z * BANDE;
      }
      p.K = 128; p.N = 128; p.op = 2; p.alpha = 1.f;
      LP(p, 3);
    }

    // 8-13. MLP per group (hidden sizes differ): geo(3,256) hyb(2,384) rea(2,512)
    const int gcnt[3] = {3, 2, 2};
    const int gbase[3] = {0, 3, 5};
    for (int grp = 0; grp < 3; ++grp) {
      int cnt = gcnt[grp], base = gbase[grp], N1 = hN[base];
      size_t hstride = (size_t)MBAND * N1;
      {  // hidden = gelu(xn @ w1 + b1)
        PArgs p{};
        p.A = xnb; p.W = w1p[base]; p.bias = b1p[base]; p.O = hid;
        for (int z = 0; z < cnt; ++z) {
          p.Aoff[z] = (size_t)(base + z) * BANDE;
          p.Woff[z] = (size_t)(w1p[base + z] - w1p[base]);
          p.boff[z] = (size_t)(b1p[base + z] - b1p[base]);
          p.Ooff[z] = z * hstride;
        }
        p.K = 128; p.N = N1; p.op = 1; p.alpha = 1.f;
        LP(p, cnt);
      }
      {  // y = x + [gate]*(hid @ w2 + b2)
        PArgs p{};
        p.A = hid; p.W = w2p[base]; p.bias = b2p[base];
        p.resid = xb; p.O = yb;
        if (grp == 0) p.extra = gateb;
        for (int z = 0; z < cnt; ++z) {
          p.Aoff[z] = z * hstride;
          p.Woff[z] = (size_t)(w2p[base + z] - w2p[base]);
          p.boff[z] = (size_t)(b2p[base + z] - b2p[base]);
          p.roff[z] = (size_t)(base + z) * BANDE;
          p.eoff[z] = z * BANDE;
          p.Ooff[z] = (size_t)(base + z) * BANDE;
        }
        p.K = N1; p.N = 128; p.op = 5; p.alpha = 1.f;
        LP(p, cnt);
      }
    }

    // 14. info, Z=6: t = z<3?z:z+1; src=6-t; i=min(t,6-t)
    {
      PArgs p{};
      p.A = yb; p.W = wp_w; p.bias = wp_b; p.O = info;
      for (int z = 0; z < 6; ++z) {
        int t = (z < 3) ? z : z + 1;
        int src = 6 - t;
        int i = (t < 3) ? t : 6 - t;
        p.Aoff[z] = (size_t)src * BANDE; p.Woff[z] = (size_t)i * 16384;
        p.boff[z] = (size_t)i * 128; p.Ooff[z] = (size_t)z * BANDE;
      }
      p.K = 128; p.N = 128; p.op = 0; p.alpha = 1.f;
      LP(p, 6);
    }

    // 15. final gates for 6 targets (2-part K)
    {
      PArgs p{};
      p.A = yb; p.W = wg_w; p.A2 = info; p.W2 = wg_w;
      p.bias = wg_b; p.resid = yb; p.extra = info; p.O = out;
      for (int z = 0; z < 6; ++z) {
        int t = (z < 3) ? z : z + 1;
        int i = (t < 3) ? t : 6 - t;
        p.Aoff[z] = (size_t)t * BANDE;  p.Woff[z] = (size_t)i * 32768;
        p.A2off[z] = (size_t)z * BANDE; p.W2off[z] = (size_t)i * 32768 + 16384;
        p.boff[z] = (size_t)i * 128;
        p.roff[z] = (size_t)t * BANDE;  p.eoff[z] = (size_t)z * BANDE;
        p.Ooff[z] = (size_t)t * BANDE;
      }
      p.K = 128; p.N = 128; p.op = 4; p.alpha = 1.f;
      LP(p, 6);
    }

    // 16-17. bridge
    bias6_kernel<<<dim3(1), dim3(128), 0, stream>>>(br_b, bbias);
    bridge_kernel<<<dim3(MBAND / 64, 2), dim3(256), 0, stream>>>(yb, br_w, bbias, bridge);

    // 18. band-3 final (2-part)
    {
      PArgs p{};
      p.A = yb; p.W = bg_w; p.A2 = bridge; p.W2 = bg_w;
      p.bias = bg_b; p.resid = yb; p.extra = bridge; p.O = out;
      p.Aoff[0] = 3 * BANDE; p.Woff[0] = 0;
      p.A2off[0] = 0; p.W2off[0] = 16384;
      p.boff[0] = 0; p.roff[0] = 3 * BANDE; p.eoff[0] = 0; p.Ooff[0] = 3 * BANDE;
      p.K = 128; p.N = 128; p.op = 4; p.alpha = 1.f;
      LP(p, 1);
    }
  } else {
    // =================== FALLBACK: per-band (63 MB, round-3 semantics) ===========
    float* yb   = ws;                         // 7 BANDE
    float* sq   = yb + 7 * BANDE;
    float* sk   = sq + BANDE;
    float* sv   = sk + BANDE;
    float* so   = sv + BANDE;
    float* shid = so + BANDE;                 // 4 BANDE
    float* bbias = shid + 4 * BANDE;          // 128

    for (int n = 0; n < NBAND; ++n) {
      const float* bn = bands + (size_t)n * BANDE;
      const float* W3[3] = {Wq + n * 16384, Wk + n * 16384, Wv + n * 16384};
      const float* b3[3] = {bq + n * 128, bk + n * 128, bv + n * 128};
      float* o3[3] = {sq, sk, sv};
      for (int w = 0; w < 3; ++w) {
        PArgs p{};
        p.A = bn; p.W = W3[w]; p.bias = b3[w]; p.O = o3[w];
        p.K = 128; p.N = 128; p.op = 0; p.alpha = 1.f;
        LP(p, 1);
      }
      attn_kernel<<<dim3(256), dim3(256), 0, stream>>>(sq, sk, sv, so);
      {
        PArgs p{};
        p.A = so; p.W = Wo + n * 16384; p.bias = bo + n * 128;
        p.resid = bn; p.O = sq;
        p.K = 128; p.N = 128; p.op = 3; p.alpha = 1.f;
        LP(p, 1);
      }
      {
        LNA p{};
        p.x = sq; p.xn = sk; p.ls[0] = lsP[n]; p.lb[0] = lbP[n];
        ln_kernel<<<dim3(MBAND / 4), dim3(256), 0, stream>>>(p);
      }
      if (n < 3) {
        PArgs p{};
        p.A = sq; p.W = g_wg + n * 16384; p.bias = g_bg + n * 128; p.O = sv;
        p.K = 128; p.N = 128; p.op = 2; p.alpha = 1.f;
        LP(p, 1);
      }
      {
        PArgs p{};
        p.A = sk; p.W = w1p[n]; p.bias = b1p[n]; p.O = shid;
        p.K = 128; p.N = hN[n]; p.op = 1; p.alpha = 1.f;
        LP(p, 1);
      }
      {
        PArgs p{};
        p.A = shid; p.W = w2p[n]; p.bias = b2p[n];
        p.resid = sq; p.O = yb; p.Ooff[0] = (size_t)n * BANDE;
        if (n < 3) p.extra = sv;
        p.K = hN[n]; p.N = 128; p.op = 5; p.alpha = 1.f;
        LP(p, 1);
      }
    }

    for (int s = 0; s < 6; ++s) {
      int t = (s < 3) ? s : s + 1;
      int i = (t < 3) ? t : 6 - t;
      int src = 6 - t;
      {
        PArgs p{};
        p.A = yb; p.Aoff[0] = (size_t)src * BANDE;
        p.W = wp_w; p.Woff[0] = (size_t)i * 16384;
        p.bias = wp_b; p.boff[0] = (size_t)i * 128;
        p.O = sq;
        p.K = 128; p.N = 128; p.op = 0; p.alpha = 1.f;
        LP(p, 1);
      }
      {
        PArgs p{};
        p.A = yb; p.Aoff[0] = (size_t)t * BANDE;
        p.W = wg_w; p.Woff[0] = (size_t)i * 32768;
        p.A2 = sq; p.W2 = wg_w; p.W2off[0] = (size_t)i * 32768 + 16384;
        p.bias = wg_b; p.boff[0] = (size_t)i * 128;
        p.resid = yb; p.roff[0] = (size_t)t * BANDE;
        p.extra = sq; p.O = out; p.Ooff[0] = (size_t)t * BANDE;
        p.K = 128; p.N = 128; p.op = 4; p.alpha = 1.f;
        LP(p, 1);
      }
    }

    bias6_kernel<<<dim3(1), dim3(128), 0, stream>>>(br_b, bbias);
    bridge_kernel<<<dim3(MBAND / 64, 2), dim3(256), 0, stream>>>(yb, br_w, bbias, sk);
    {
      PArgs p{};
      p.A = yb; p.Aoff[0] = 3 * BANDE; p.W = bg_w;
      p.A2 = sk; p.W2 = bg_w; p.W2off[0] = 16384;
      p.bias = bg_b; p.resid = yb; p.roff[0] = 3 * BANDE;
      p.extra = sk; p.O = out; p.Ooff[0] = 3 * BANDE;
      p.K = 128; p.N = 128; p.op = 4; p.alpha = 1.f;
      LP(p, 1);
    }
  }
}

// Round 5
// 806.790 us; speedup vs baseline: 2.5875x; 1.3170x over previous
//
#include <hip/hip_runtime.h>
#include <hip/hip_bf16.h>

#define NBAND 7
#define BBATCH 16
#define TSEQ 512
#define DMODEL 128
#define MBAND (BBATCH * TSEQ)               // 8192 rows per band
#define BANDE ((size_t)MBAND * DMODEL)      // 1,048,576 elements per band

typedef __attribute__((ext_vector_type(8))) short short8;
typedef __attribute__((ext_vector_type(4))) float f32x4;

__device__ __forceinline__ unsigned short f2bf(float x) {
  unsigned u = __float_as_uint(x);
  unsigned r = u + 0x7FFF + ((u >> 16) & 1);   // RNE
  return (unsigned short)(r >> 16);
}

// ---------------------------------------------------------------------------
// MFMA part: acc[2][2] (+=) A(64xK, fp32) @ W(KxN fp32) for this block's
// 64x64 tile at (m0,n0). 256 threads = 4 waves in 2x2; per wave 32x32 via
// 2x2 mfma_f32_16x16x32_bf16 fragments. fp32 -> bf16 at staging time.
// As: [m][k] bf16, Bs: [n][k] bf16 (transposed); rows 80 B (16B-aligned b128).
// ---------------------------------------------------------------------------
__device__ __forceinline__ void mfma_part(const float* __restrict__ A,
                                          const float* __restrict__ W,
                                          int K, int N, int m0, int n0, int tid,
                                          unsigned short (*As)[40],
                                          unsigned short (*Bs)[40],
                                          f32x4 acc[2][2]) {
  const int lane = tid & 63;
  const int wv = tid >> 6;
  const int wr = wv >> 1, wc = wv & 1;
  const int lr = lane & 15, k8 = lane >> 4;

  for (int k0 = 0; k0 < K; k0 += 32) {
    // stage A: 64 m x 32 k, float4 loads, bf16 stores
    #pragma unroll
    for (int it = 0; it < 2; ++it) {
      int t = tid + it * 256;               // 0..511
      int m = t >> 3, kq = (t & 7) << 2;
      const float4 v = *(const float4*)&A[(size_t)(m0 + m) * K + k0 + kq];
      unsigned short* dst = &As[m][kq];
      dst[0] = f2bf(v.x); dst[1] = f2bf(v.y); dst[2] = f2bf(v.z); dst[3] = f2bf(v.w);
    }
    // stage B transposed: 32 k x 64 n
    #pragma unroll
    for (int it = 0; it < 2; ++it) {
      int t = tid + it * 256;
      int k = t >> 4, nq = (t & 15) << 2;
      const float4 v = *(const float4*)&W[(size_t)(k0 + k) * N + n0 + nq];
      Bs[nq + 0][k] = f2bf(v.x); Bs[nq + 1][k] = f2bf(v.y);
      Bs[nq + 2][k] = f2bf(v.z); Bs[nq + 3][k] = f2bf(v.w);
    }
    __syncthreads();
    short8 a0 = *(const short8*)&As[wr * 32 + lr][k8 * 8];
    short8 a1 = *(const short8*)&As[wr * 32 + 16 + lr][k8 * 8];
    short8 b0 = *(const short8*)&Bs[wc * 32 + lr][k8 * 8];
    short8 b1 = *(const short8*)&Bs[wc * 32 + 16 + lr][k8 * 8];
    acc[0][0] = __builtin_amdgcn_mfma_f32_16x16x32_bf16(a0, b0, acc[0][0], 0, 0, 0);
    acc[0][1] = __builtin_amdgcn_mfma_f32_16x16x32_bf16(a0, b1, acc[0][1], 0, 0, 0);
    acc[1][0] = __builtin_amdgcn_mfma_f32_16x16x32_bf16(a1, b0, acc[1][0], 0, 0, 0);
    acc[1][1] = __builtin_amdgcn_mfma_f32_16x16x32_bf16(a1, b1, acc[1][1], 0, 0, 0);
    __syncthreads();
  }
}

// ---------------------------------------------------------------------------
// Batched GEMM over blockIdx.z:  C_z = epi( alpha*(A_z@W_z [+ A2_z@W2_z]) + b_z )
// ---------------------------------------------------------------------------
struct PArgs {
  const float *A, *W, *bias, *A2, *W2, *resid, *extra;
  float* O;
  size_t Aoff[8], Woff[8], boff[8], A2off[8], W2off[8], roff[8], eoff[8], Ooff[8];
  int K, N, op;     // 0 store 1 gelu 2 sigmoid 3 resid+ 4 resid+sig(v)*extra 5 resid+extra*v
  float alpha;
};

__global__ __launch_bounds__(256) void gemm_b(PArgs p) {
  __shared__ __align__(16) unsigned short As[64][40];
  __shared__ __align__(16) unsigned short Bs[64][40];
  const int z = blockIdx.z;
  const int m0 = blockIdx.x * 64, n0 = blockIdx.y * 64;
  const int tid = threadIdx.x;
  f32x4 acc[2][2] = {};

  mfma_part(p.A + p.Aoff[z], p.W + p.Woff[z], p.K, p.N, m0, n0, tid, As, Bs, acc);
  if (p.A2)
    mfma_part(p.A2 + p.A2off[z], p.W2 + p.W2off[z], p.K, p.N, m0, n0, tid, As, Bs, acc);

  const float* bias  = p.bias  ? p.bias  + p.boff[z] : nullptr;
  const float* resid = p.resid ? p.resid + p.roff[z] : nullptr;
  const float* extra = p.extra ? p.extra + p.eoff[z] : nullptr;
  float* O = p.O + p.Ooff[z];

  const int lane = tid & 63;
  const int wv = tid >> 6;
  const int wr = wv >> 1, wc = wv & 1;
  const int lr = lane & 15, lg = lane >> 4;

  #pragma unroll
  for (int i = 0; i < 2; ++i) {
    #pragma unroll
    for (int j = 0; j < 2; ++j) {
      #pragma unroll
      for (int r = 0; r < 4; ++r) {
        int m = m0 + wr * 32 + i * 16 + lg * 4 + r;
        int n = n0 + wc * 32 + j * 16 + lr;
        float v = acc[i][j][r] * p.alpha;
        if (bias) v += bias[n];
        size_t idx = (size_t)m * p.N + n;
        switch (p.op) {
          case 0: O[idx] = v; break;
          case 1: O[idx] = 0.5f * v * (1.f + erff(v * 0.70710678118654752f)); break;
          case 2: O[idx] = 1.f / (1.f + __expf(-v)); break;
          case 3: O[idx] = resid[idx] + v; break;
          case 4: {
            float gate = 1.f / (1.f + __expf(-v));
            O[idx] = resid[idx] + gate * extra[idx];
          } break;
          case 5: {
            float gm = extra ? extra[idx] : 1.f;
            O[idx] = resid[idx] + gm * v;
          } break;
        }
      }
    }
  }
}

// 6-part bridge: O = (sum_j y[bl_j] @ br_w[j]) / 6 + bbias   (bbias = sum(br_b)/6)
__global__ __launch_bounds__(256) void bridge_kernel(const float* __restrict__ yb,
                                                     const float* __restrict__ br_w,
                                                     const float* __restrict__ bbias,
                                                     float* __restrict__ O) {
  __shared__ __align__(16) unsigned short As[64][40];
  __shared__ __align__(16) unsigned short Bs[64][40];
  const int m0 = blockIdx.x * 64, n0 = blockIdx.y * 64;
  const int tid = threadIdx.x;
  f32x4 acc[2][2] = {};
  const int bl[6] = {0, 1, 2, 4, 5, 6};
  for (int j = 0; j < 6; ++j)
    mfma_part(yb + (size_t)bl[j] * BANDE, br_w + j * 16384, 128, 128, m0, n0, tid, As, Bs, acc);

  const int lane = tid & 63;
  const int wv = tid >> 6;
  const int wr = wv >> 1, wc = wv & 1;
  const int lr = lane & 15, lg = lane >> 4;
  #pragma unroll
  for (int i = 0; i < 2; ++i)
    #pragma unroll
    for (int j = 0; j < 2; ++j)
      #pragma unroll
      for (int r = 0; r < 4; ++r) {
        int m = m0 + wr * 32 + i * 16 + lg * 4 + r;
        int n = n0 + wc * 32 + j * 16 + lr;
        O[(size_t)m * 128 + n] = acc[i][j][r] * (1.f / 6.f) + bbias[n];
      }
}

// ---------------------------------------------------------------------------
// Flash-style causal attention, fp32. H=2, HD=64, T=512, multi-band.
// (unchanged from round 4)
// ---------------------------------------------------------------------------
__global__ __launch_bounds__(256) void attn_kernel(const float* __restrict__ q,
                                                   const float* __restrict__ k,
                                                   const float* __restrict__ v,
                                                   float* __restrict__ o) {
  const int band = blockIdx.x >> 8;
  const int rest = blockIdx.x & 255;
  const int qt = rest & 7;
  const int bh = rest >> 3;
  const int h  = bh & 1;
  const int b  = bh >> 1;
  const size_t rowbase = ((size_t)band * BBATCH + b) * TSEQ;

  const int tid = threadIdx.x;
  const int r = tid >> 2;
  const int c = tid & 3;
  const int qrow = qt * 64 + r;

  __shared__ float Kt[64][64];
  __shared__ float Vt[64][64];

  float qreg[16];
  {
    const float* qp = q + (rowbase + qrow) * DMODEL + h * 64 + c * 16;
    #pragma unroll
    for (int i = 0; i < 16; ++i) qreg[i] = qp[i] * 0.125f;  // 1/sqrt(64)
  }

  float m = -1e30f, l = 0.f;
  float outv[16];
  #pragma unroll
  for (int i = 0; i < 16; ++i) outv[i] = 0.f;

  for (int kt = 0; kt <= qt; ++kt) {
    __syncthreads();
    #pragma unroll
    for (int i = 0; i < 16; ++i) {
      int f = tid + i * 256;                    // 4096 = 64x64
      int s_ = f >> 6, dd = f & 63;
      size_t gidx = (rowbase + kt * 64 + s_) * DMODEL + h * 64 + dd;
      Kt[s_][dd] = k[gidx];
      Vt[s_][dd] = v[gidx];
    }
    __syncthreads();

    for (int ch = 0; ch < 4; ++ch) {
      float sc[16];
      #pragma unroll
      for (int j = 0; j < 16; ++j) {
        int key = ch * 16 + j;
        float p = 0.f;
        #pragma unroll
        for (int i = 0; i < 16; ++i) p += qreg[i] * Kt[key][c * 16 + i];
        p += __shfl_xor(p, 1);
        p += __shfl_xor(p, 2);
        int gkey = kt * 64 + key;
        sc[j] = (gkey <= qrow) ? p : -1e30f;
      }
      float mx = m;
      #pragma unroll
      for (int j = 0; j < 16; ++j) mx = fmaxf(mx, sc[j]);
      float alpha = __expf(m - mx);
      l *= alpha;
      #pragma unroll
      for (int i = 0; i < 16; ++i) outv[i] *= alpha;
      #pragma unroll
      for (int j = 0; j < 16; ++j) {
        float p = __expf(sc[j] - mx);
        l += p;
        int key = ch * 16 + j;
        #pragma unroll
        for (int i = 0; i < 16; ++i) outv[i] += p * Vt[key][c * 16 + i];
      }
      m = mx;
    }
  }

  float inv = 1.f / l;
  float* op = o + (rowbase + qrow) * DMODEL + h * 64 + c * 16;
  #pragma unroll
  for (int i = 0; i < 16; ++i) op[i] = outv[i] * inv;
}

// ---------------------------------------------------------------------------
// LayerNorm over last dim (128), band-indexed scale/bias (band = row>>13).
// ---------------------------------------------------------------------------
struct LNA {
  const float* x;
  float* xn;
  const float* ls[7];
  const float* lb[7];
};

__global__ __launch_bounds__(256) void ln_kernel(LNA p) {
  const int tid = threadIdx.x;
  const int rr = tid >> 6, lane = tid & 63;
  const size_t row = (size_t)blockIdx.x * 4 + rr;
  const float* xp = p.x + row * DMODEL;
  float a = xp[lane], b = xp[lane + 64];
  float s = a + b;
  #pragma unroll
  for (int off = 32; off; off >>= 1) s += __shfl_xor(s, off);
  float mean = s * (1.f / 128.f);
  float da = a - mean, db = b - mean;
  float vs = da * da + db * db;
  #pragma unroll
  for (int off = 32; off; off >>= 1) vs += __shfl_xor(vs, off);
  float rstd = rsqrtf(vs * (1.f / 128.f) + 1e-5f);
  int band = (int)(row >> 13);
  const float* ls = p.ls[band];
  const float* lb = p.lb[band];
  float* op = p.xn + row * DMODEL;
  op[lane]      = da * rstd * ls[lane]      + lb[lane];
  op[lane + 64] = db * rstd * ls[lane + 64] + lb[lane + 64];
}

__global__ void bias6_kernel(const float* __restrict__ br_b, float* __restrict__ out) {
  int d = threadIdx.x;
  float s = 0.f;
  #pragma unroll
  for (int j = 0; j < 6; ++j) s += br_b[j * 128 + d];
  out[d] = s * (1.f / 6.f);
}

// ---------------------------------------------------------------------------
extern "C" void kernel_launch(void* const* d_in, const int* in_sizes, int n_in,
                              void* d_out, int out_size, void* d_ws, size_t ws_size,
                              hipStream_t stream) {
  bool dict = (in_sizes[2] != 896);
  const float* bands = (const float*)d_in[0];
  const float* Wq = (const float*)d_in[1];
  const float *Wk, *Wv, *Wo, *bq, *bk, *bv, *bo;
  if (dict) {
    Wk = (const float*)d_in[2]; Wv = (const float*)d_in[3]; Wo = (const float*)d_in[4];
    bq = (const float*)d_in[5]; bk = (const float*)d_in[6];
    bv = (const float*)d_in[7]; bo = (const float*)d_in[8];
  } else {
    bq = (const float*)d_in[2]; Wk = (const float*)d_in[3]; bk = (const float*)d_in[4];
    Wv = (const float*)d_in[5]; bv = (const float*)d_in[6];
    Wo = (const float*)d_in[7]; bo = (const float*)d_in[8];
  }
  const float* g_ls = (const float*)d_in[9];
  const float* g_lb = (const float*)d_in[10];
  const float* g_w1 = (const float*)d_in[11];
  const float* g_b1 = (const float*)d_in[12];
  const float* g_w2 = (const float*)d_in[13];
  const float* g_b2 = (const float*)d_in[14];
  const float* g_wg = (const float*)d_in[15];
  const float* g_bg = (const float*)d_in[16];
  const float* h_ls = (const float*)d_in[17];
  const float* h_lb = (const float*)d_in[18];
  const float* h_w1 = (const float*)d_in[19];
  const float* h_b1 = (const float*)d_in[20];
  const float* h_w2 = (const float*)d_in[21];
  const float* h_b2 = (const float*)d_in[22];
  const float* r_ls = (const float*)d_in[23];
  const float* r_lb = (const float*)d_in[24];
  const float* r_w1 = (const float*)d_in[25];
  const float* r_b1 = (const float*)d_in[26];
  const float* r_w2 = (const float*)d_in[27];
  const float* r_b2 = (const float*)d_in[28];
  const float* wp_w = (const float*)d_in[29];
  const float* wp_b = (const float*)d_in[30];
  const float* wg_w = (const float*)d_in[31];
  const float* wg_b = (const float*)d_in[32];
  const float* br_w = (const float*)d_in[33];
  const float* br_b = (const float*)d_in[34];
  const float* bg_w = (const float*)d_in[35];
  const float* bg_b = (const float*)d_in[36];
  float* out = (float*)d_out;

  const int hN[7] = {256, 256, 256, 384, 384, 512, 512};
  const float* lsP[7] = {g_ls, g_ls + 128, g_ls + 256, h_ls, h_ls + 128, r_ls, r_ls + 128};
  const float* lbP[7] = {g_lb, g_lb + 128, g_lb + 256, h_lb, h_lb + 128, r_lb, r_lb + 128};
  const float* w1p[7] = {g_w1, g_w1 + 32768, g_w1 + 65536,
                         h_w1, h_w1 + 49152, r_w1, r_w1 + 65536};
  const float* b1p[7] = {g_b1, g_b1 + 256, g_b1 + 512,
                         h_b1, h_b1 + 384, r_b1, r_b1 + 512};
  const float* w2p[7] = {g_w2, g_w2 + 32768, g_w2 + 65536,
                         h_w2, h_w2 + 49152, r_w2, r_w2 + 65536};
  const float* b2p[7] = {g_b2, g_b2 + 128, g_b2 + 256,
                         h_b2, h_b2 + 128, r_b2, r_b2 + 128};

  auto LP = [&](PArgs& p, int Z) {
    dim3 grid(MBAND / 64, p.N / 64, Z);
    gemm_b<<<grid, dim3(256), 0, stream>>>(p);
  };

  float* ws = (float*)d_ws;
  const size_t needFast = (36 * BANDE + 256) * sizeof(float);   // ~151 MB

  if (ws_size >= needFast) {
    // =================== FAST PATH: all bands batched ===================
    float* qb  = ws;                 // 7 BANDE   (later: x)
    float* kb  = qb + 7 * BANDE;     // 7 BANDE   (later: xn)
    float* vb  = kb + 7 * BANDE;     // 7 BANDE   (later: gate, 3 used)
    float* ob  = vb + 7 * BANDE;     // 7 BANDE   (later: y)
    float* hid = ob + 7 * BANDE;     // 8 BANDE   (later: info 6 + bridge 1)
    float* bbias = hid + 8 * BANDE;  // 128
    float* xb = qb;
    float* xnb = kb;
    float* gateb = vb;
    float* yb = ob;
    float* info = hid;
    float* bridge = hid + 6 * BANDE;

    // 1-3. Q/K/V projections, Z=7 each
    const float* Wqkv[3] = {Wq, Wk, Wv};
    const float* bqkv[3] = {bq, bk, bv};
    float* oqkv[3] = {qb, kb, vb};
    for (int w = 0; w < 3; ++w) {
      PArgs p{};
      p.A = bands; p.W = Wqkv[w]; p.bias = bqkv[w]; p.O = oqkv[w];
      for (int z = 0; z < 7; ++z) {
        p.Aoff[z] = z * BANDE; p.Woff[z] = (size_t)z * 16384;
        p.boff[z] = (size_t)z * 128; p.Ooff[z] = z * BANDE;
      }
      p.K = 128; p.N = 128; p.op = 0; p.alpha = 1.f;
      LP(p, 7);
    }

    // 4. attention, all bands
    attn_kernel<<<dim3(NBAND * 256), dim3(256), 0, stream>>>(qb, kb, vb, ob);

    // 5. x = bands + o @ Wo + bo  (-> qb region)
    {
      PArgs p{};
      p.A = ob; p.W = Wo; p.bias = bo; p.resid = bands; p.O = xb;
      for (int z = 0; z < 7; ++z) {
        p.Aoff[z] = z * BANDE; p.Woff[z] = (size_t)z * 16384;
        p.boff[z] = (size_t)z * 128; p.roff[z] = z * BANDE; p.Ooff[z] = z * BANDE;
      }
      p.K = 128; p.N = 128; p.op = 3; p.alpha = 1.f;
      LP(p, 7);
    }

    // 6. LN all bands
    {
      LNA p{};
      p.x = xb; p.xn = xnb;
      for (int n = 0; n < 7; ++n) { p.ls[n] = lsP[n]; p.lb[n] = lbP[n]; }
      ln_kernel<<<dim3(NBAND * MBAND / 4), dim3(256), 0, stream>>>(p);
    }

    // 7. geo gates, Z=3
    {
      PArgs p{};
      p.A = xb; p.W = g_wg; p.bias = g_bg; p.O = gateb;
      for (int z = 0; z < 3; ++z) {
        p.Aoff[z] = z * BANDE; p.Woff[z] = (size_t)z * 16384;
        p.boff[z] = (size_t)z * 128; p.Ooff[z] = z * BANDE;
      }
      p.K = 128; p.N = 128; p.op = 2; p.alpha = 1.f;
      LP(p, 3);
    }

    // 8-13. MLP per group: geo(3,256) hyb(2,384) rea(2,512)
    const int gcnt[3] = {3, 2, 2};
    const int gbase[3] = {0, 3, 5};
    for (int grp = 0; grp < 3; ++grp) {
      int cnt = gcnt[grp], base = gbase[grp], N1 = hN[base];
      size_t hstride = (size_t)MBAND * N1;
      {  // hidden = gelu(xn @ w1 + b1)
        PArgs p{};
        p.A = xnb; p.W = w1p[base]; p.bias = b1p[base]; p.O = hid;
        for (int z = 0; z < cnt; ++z) {
          p.Aoff[z] = (size_t)(base + z) * BANDE;
          p.Woff[z] = (size_t)(w1p[base + z] - w1p[base]);
          p.boff[z] = (size_t)(b1p[base + z] - b1p[base]);
          p.Ooff[z] = z * hstride;
        }
        p.K = 128; p.N = N1; p.op = 1; p.alpha = 1.f;
        LP(p, cnt);
      }
      {  // y = x + [gate]*(hid @ w2 + b2)
        PArgs p{};
        p.A = hid; p.W = w2p[base]; p.bias = b2p[base];
        p.resid = xb; p.O = yb;
        if (grp == 0) p.extra = gateb;
        for (int z = 0; z < cnt; ++z) {
          p.Aoff[z] = z * hstride;
          p.Woff[z] = (size_t)(w2p[base + z] - w2p[base]);
          p.boff[z] = (size_t)(b2p[base + z] - b2p[base]);
          p.roff[z] = (size_t)(base + z) * BANDE;
          p.eoff[z] = z * BANDE;
          p.Ooff[z] = (size_t)(base + z) * BANDE;
        }
        p.K = N1; p.N = 128; p.op = 5; p.alpha = 1.f;
        LP(p, cnt);
      }
    }

    // 14. info, Z=6
    {
      PArgs p{};
      p.A = yb; p.W = wp_w; p.bias = wp_b; p.O = info;
      for (int z = 0; z < 6; ++z) {
        int t = (z < 3) ? z : z + 1;
        int src = 6 - t;
        int i = (t < 3) ? t : 6 - t;
        p.Aoff[z] = (size_t)src * BANDE; p.Woff[z] = (size_t)i * 16384;
        p.boff[z] = (size_t)i * 128; p.Ooff[z] = (size_t)z * BANDE;
      }
      p.K = 128; p.N = 128; p.op = 0; p.alpha = 1.f;
      LP(p, 6);
    }

    // 15. final gates for 6 targets (2-part K)
    {
      PArgs p{};
      p.A = yb; p.W = wg_w; p.A2 = info; p.W2 = wg_w;
      p.bias = wg_b; p.resid = yb; p.extra = info; p.O = out;
      for (int z = 0; z < 6; ++z) {
        int t = (z < 3) ? z : z + 1;
        int i = (t < 3) ? t : 6 - t;
        p.Aoff[z] = (size_t)t * BANDE;  p.Woff[z] = (size_t)i * 32768;
        p.A2off[z] = (size_t)z * BANDE; p.W2off[z] = (size_t)i * 32768 + 16384;
        p.boff[z] = (size_t)i * 128;
        p.roff[z] = (size_t)t * BANDE;  p.eoff[z] = (size_t)z * BANDE;
        p.Ooff[z] = (size_t)t * BANDE;
      }
      p.K = 128; p.N = 128; p.op = 4; p.alpha = 1.f;
      LP(p, 6);
    }

    // 16-17. bridge
    bias6_kernel<<<dim3(1), dim3(128), 0, stream>>>(br_b, bbias);
    bridge_kernel<<<dim3(MBAND / 64, 2), dim3(256), 0, stream>>>(yb, br_w, bbias, bridge);

    // 18. band-3 final (2-part)
    {
      PArgs p{};
      p.A = yb; p.W = bg_w; p.A2 = bridge; p.W2 = bg_w;
      p.bias = bg_b; p.resid = yb; p.extra = bridge; p.O = out;
      p.Aoff[0] = 3 * BANDE; p.Woff[0] = 0;
      p.A2off[0] = 0; p.W2off[0] = 16384;
      p.boff[0] = 0; p.roff[0] = 3 * BANDE; p.eoff[0] = 0; p.Ooff[0] = 3 * BANDE;
      p.K = 128; p.N = 128; p.op = 4; p.alpha = 1.f;
      LP(p, 1);
    }
  } else {
    // =================== FALLBACK: per-band (63 MB) ===================
    float* yb   = ws;                         // 7 BANDE
    float* sq   = yb + 7 * BANDE;
    float* sk   = sq + BANDE;
    float* sv   = sk + BANDE;
    float* so   = sv + BANDE;
    float* shid = so + BANDE;                 // 4 BANDE
    float* bbias = shid + 4 * BANDE;          // 128

    for (int n = 0; n < NBAND; ++n) {
      const float* bn = bands + (size_t)n * BANDE;
      const float* W3[3] = {Wq + n * 16384, Wk + n * 16384, Wv + n * 16384};
      const float* b3[3] = {bq + n * 128, bk + n * 128, bv + n * 128};
      float* o3[3] = {sq, sk, sv};
      for (int w = 0; w < 3; ++w) {
        PArgs p{};
        p.A = bn; p.W = W3[w]; p.bias = b3[w]; p.O = o3[w];
        p.K = 128; p.N = 128; p.op = 0; p.alpha = 1.f;
        LP(p, 1);
      }
      attn_kernel<<<dim3(256), dim3(256), 0, stream>>>(sq, sk, sv, so);
      {
        PArgs p{};
        p.A = so; p.W = Wo + n * 16384; p.bias = bo + n * 128;
        p.resid = bn; p.O = sq;
        p.K = 128; p.N = 128; p.op = 3; p.alpha = 1.f;
        LP(p, 1);
      }
      {
        LNA p{};
        p.x = sq; p.xn = sk; p.ls[0] = lsP[n]; p.lb[0] = lbP[n];
        ln_kernel<<<dim3(MBAND / 4), dim3(256), 0, stream>>>(p);
      }
      if (n < 3) {
        PArgs p{};
        p.A = sq; p.W = g_wg + n * 16384; p.bias = g_bg + n * 128; p.O = sv;
        p.K = 128; p.N = 128; p.op = 2; p.alpha = 1.f;
        LP(p, 1);
      }
      {
        PArgs p{};
        p.A = sk; p.W = w1p[n]; p.bias = b1p[n]; p.O = shid;
        p.K = 128; p.N = hN[n]; p.op = 1; p.alpha = 1.f;
        LP(p, 1);
      }
      {
        PArgs p{};
        p.A = shid; p.W = w2p[n]; p.bias = b2p[n];
        p.resid = sq; p.O = yb; p.Ooff[0] = (size_t)n * BANDE;
        if (n < 3) p.extra = sv;
        p.K = hN[n]; p.N = 128; p.op = 5; p.alpha = 1.f;
        LP(p, 1);
      }
    }

    for (int s = 0; s < 6; ++s) {
      int t = (s < 3) ? s : s + 1;
      int i = (t < 3) ? t : 6 - t;
      int src = 6 - t;
      {
        PArgs p{};
        p.A = yb; p.Aoff[0] = (size_t)src * BANDE;
        p.W = wp_w; p.Woff[0] = (size_t)i * 16384;
        p.bias = wp_b; p.boff[0] = (size_t)i * 128;
        p.O = sq;
        p.K = 128; p.N = 128; p.op = 0; p.alpha = 1.f;
        LP(p, 1);
      }
      {
        PArgs p{};
        p.A = yb; p.Aoff[0] = (size_t)t * BANDE;
        p.W = wg_w; p.Woff[0] = (size_t)i * 32768;
        p.A2 = sq; p.W2 = wg_w; p.W2off[0] = (size_t)i * 32768 + 16384;
        p.bias = wg_b; p.boff[0] = (size_t)i * 128;
        p.resid = yb; p.roff[0] = (size_t)t * BANDE;
        p.extra = sq; p.O = out; p.Ooff[0] = (size_t)t * BANDE;
        p.K = 128; p.N = 128; p.op = 4; p.alpha = 1.f;
        LP(p, 1);
      }
    }

    bias6_kernel<<<dim3(1), dim3(128), 0, stream>>>(br_b, bbias);
    bridge_kernel<<<dim3(MBAND / 64, 2), dim3(256), 0, stream>>>(yb, br_w, bbias, sk);
    {
      PArgs p{};
      p.A = yb; p.Aoff[0] = 3 * BANDE; p.W = bg_w;
      p.A2 = sk; p.W2 = bg_w; p.W2off[0] = 16384;
      p.bias = bg_b; p.resid = yb; p.roff[0] = 3 * BANDE;
      p.extra = sk; p.O = out; p.Ooff[0] = 3 * BANDE;
      p.K = 128; p.N = 128; p.op = 4; p.alpha = 1.f;
      LP(p, 1);
    }
  }
}

// Round 6
// 437.966 us; speedup vs baseline: 4.7665x; 1.8421x over previous
//
#include <hip/hip_runtime.h>
#include <hip/hip_bf16.h>

#define NBAND 7
#define BBATCH 16
#define TSEQ 512
#define DMODEL 128
#define MBAND (BBATCH * TSEQ)               // 8192 rows per band
#define BANDE ((size_t)MBAND * DMODEL)      // 1,048,576 elements per band

typedef __attribute__((ext_vector_type(8))) short short8;
typedef __attribute__((ext_vector_type(4))) float f32x4;

__device__ __forceinline__ unsigned short f2bf(float x) {
  unsigned u = __float_as_uint(x);
  unsigned r = u + 0x7FFF + ((u >> 16) & 1);   // RNE
  return (unsigned short)(r >> 16);
}

// ---------------------------------------------------------------------------
// MFMA part: acc[2][2] (+=) A(64xK, fp32) @ W(KxN fp32) for this block's
// 64x64 tile at (m0,n0). 256 threads = 4 waves in 2x2; per wave 32x32 via
// 2x2 mfma_f32_16x16x32_bf16 fragments. fp32 -> bf16 at staging time.
// ---------------------------------------------------------------------------
__device__ __forceinline__ void mfma_part(const float* __restrict__ A,
                                          const float* __restrict__ W,
                                          int K, int N, int m0, int n0, int tid,
                                          unsigned short (*As)[40],
                                          unsigned short (*Bs)[40],
                                          f32x4 acc[2][2]) {
  const int lane = tid & 63;
  const int wv = tid >> 6;
  const int wr = wv >> 1, wc = wv & 1;
  const int lr = lane & 15, k8 = lane >> 4;

  for (int k0 = 0; k0 < K; k0 += 32) {
    #pragma unroll
    for (int it = 0; it < 2; ++it) {
      int t = tid + it * 256;               // 0..511
      int m = t >> 3, kq = (t & 7) << 2;
      const float4 v = *(const float4*)&A[(size_t)(m0 + m) * K + k0 + kq];
      unsigned short* dst = &As[m][kq];
      dst[0] = f2bf(v.x); dst[1] = f2bf(v.y); dst[2] = f2bf(v.z); dst[3] = f2bf(v.w);
    }
    #pragma unroll
    for (int it = 0; it < 2; ++it) {
      int t = tid + it * 256;
      int k = t >> 4, nq = (t & 15) << 2;
      const float4 v = *(const float4*)&W[(size_t)(k0 + k) * N + n0 + nq];
      Bs[nq + 0][k] = f2bf(v.x); Bs[nq + 1][k] = f2bf(v.y);
      Bs[nq + 2][k] = f2bf(v.z); Bs[nq + 3][k] = f2bf(v.w);
    }
    __syncthreads();
    short8 a0 = *(const short8*)&As[wr * 32 + lr][k8 * 8];
    short8 a1 = *(const short8*)&As[wr * 32 + 16 + lr][k8 * 8];
    short8 b0 = *(const short8*)&Bs[wc * 32 + lr][k8 * 8];
    short8 b1 = *(const short8*)&Bs[wc * 32 + 16 + lr][k8 * 8];
    acc[0][0] = __builtin_amdgcn_mfma_f32_16x16x32_bf16(a0, b0, acc[0][0], 0, 0, 0);
    acc[0][1] = __builtin_amdgcn_mfma_f32_16x16x32_bf16(a0, b1, acc[0][1], 0, 0, 0);
    acc[1][0] = __builtin_amdgcn_mfma_f32_16x16x32_bf16(a1, b0, acc[1][0], 0, 0, 0);
    acc[1][1] = __builtin_amdgcn_mfma_f32_16x16x32_bf16(a1, b1, acc[1][1], 0, 0, 0);
    __syncthreads();
  }
}

// ---------------------------------------------------------------------------
// Batched GEMM over blockIdx.z:  C_z = epi( alpha*(A_z@W_z [+ A2_z@W2_z]) + b_z )
// ---------------------------------------------------------------------------
struct PArgs {
  const float *A, *W, *bias, *A2, *W2, *resid, *extra;
  float* O;
  size_t Aoff[8], Woff[8], boff[8], A2off[8], W2off[8], roff[8], eoff[8], Ooff[8];
  int K, N, op;     // 0 store 1 gelu 2 sigmoid 3 resid+ 4 resid+sig(v)*extra 5 resid+extra*v
  float alpha;
};

__global__ __launch_bounds__(256) void gemm_b(PArgs p) {
  __shared__ __align__(16) unsigned short As[64][40];
  __shared__ __align__(16) unsigned short Bs[64][40];
  const int z = blockIdx.z;
  const int m0 = blockIdx.x * 64, n0 = blockIdx.y * 64;
  const int tid = threadIdx.x;
  f32x4 acc[2][2] = {};

  mfma_part(p.A + p.Aoff[z], p.W + p.Woff[z], p.K, p.N, m0, n0, tid, As, Bs, acc);
  if (p.A2)
    mfma_part(p.A2 + p.A2off[z], p.W2 + p.W2off[z], p.K, p.N, m0, n0, tid, As, Bs, acc);

  const float* bias  = p.bias  ? p.bias  + p.boff[z] : nullptr;
  const float* resid = p.resid ? p.resid + p.roff[z] : nullptr;
  const float* extra = p.extra ? p.extra + p.eoff[z] : nullptr;
  float* O = p.O + p.Ooff[z];

  const int lane = tid & 63;
  const int wv = tid >> 6;
  const int wr = wv >> 1, wc = wv & 1;
  const int lr = lane & 15, lg = lane >> 4;

  #pragma unroll
  for (int i = 0; i < 2; ++i) {
    #pragma unroll
    for (int j = 0; j < 2; ++j) {
      #pragma unroll
      for (int r = 0; r < 4; ++r) {
        int m = m0 + wr * 32 + i * 16 + lg * 4 + r;
        int n = n0 + wc * 32 + j * 16 + lr;
        float v = acc[i][j][r] * p.alpha;
        if (bias) v += bias[n];
        size_t idx = (size_t)m * p.N + n;
        switch (p.op) {
          case 0: O[idx] = v; break;
          case 1: O[idx] = 0.5f * v * (1.f + erff(v * 0.70710678118654752f)); break;
          case 2: O[idx] = 1.f / (1.f + __expf(-v)); break;
          case 3: O[idx] = resid[idx] + v; break;
          case 4: {
            float gate = 1.f / (1.f + __expf(-v));
            O[idx] = resid[idx] + gate * extra[idx];
          } break;
          case 5: {
            float gm = extra ? extra[idx] : 1.f;
            O[idx] = resid[idx] + gm * v;
          } break;
        }
      }
    }
  }
}

// 6-part bridge: O = (sum_j y[bl_j] @ br_w[j]) / 6 + bbias   (bbias = sum(br_b)/6)
__global__ __launch_bounds__(256) void bridge_kernel(const float* __restrict__ yb,
                                                     const float* __restrict__ br_w,
                                                     const float* __restrict__ bbias,
                                                     float* __restrict__ O) {
  __shared__ __align__(16) unsigned short As[64][40];
  __shared__ __align__(16) unsigned short Bs[64][40];
  const int m0 = blockIdx.x * 64, n0 = blockIdx.y * 64;
  const int tid = threadIdx.x;
  f32x4 acc[2][2] = {};
  const int bl[6] = {0, 1, 2, 4, 5, 6};
  for (int j = 0; j < 6; ++j)
    mfma_part(yb + (size_t)bl[j] * BANDE, br_w + j * 16384, 128, 128, m0, n0, tid, As, Bs, acc);

  const int lane = tid & 63;
  const int wv = tid >> 6;
  const int wr = wv >> 1, wc = wv & 1;
  const int lr = lane & 15, lg = lane >> 4;
  #pragma unroll
  for (int i = 0; i < 2; ++i)
    #pragma unroll
    for (int j = 0; j < 2; ++j)
      #pragma unroll
      for (int r = 0; r < 4; ++r) {
        int m = m0 + wr * 32 + i * 16 + lg * 4 + r;
        int n = n0 + wc * 32 + j * 16 + lr;
        O[(size_t)m * 128 + n] = acc[i][j][r] * (1.f / 6.f) + bbias[n];
      }
}

// ---------------------------------------------------------------------------
// MFMA flash attention, causal. H=2, HD=64, T=512, multi-band.
// grid.x = nbands*256: band = bx>>8, qt = bx&7, bh = (bx>>3)&31.
// 4 waves; wave w owns q-rows [qt*64 + w*16, +16) x all 64 dims.
// Per k-tile (64 keys): QK^T (8 mfma) -> online softmax (in C/D layout,
// row-stats per accumulator reg, shfl within 16-lane groups) -> P to
// per-wave LDS (C/D -> A-operand transpose) -> PV (8 mfma).
// ---------------------------------------------------------------------------
__global__ __launch_bounds__(256) void attn_kernel(const float* __restrict__ q,
                                                   const float* __restrict__ k,
                                                   const float* __restrict__ v,
                                                   float* __restrict__ o) {
  const int band = blockIdx.x >> 8;
  const int rest = blockIdx.x & 255;
  const int qt = rest & 7;
  const int bh = rest >> 3;
  const int h  = bh & 1;
  const int b  = bh >> 1;
  const size_t rowbase = ((size_t)band * BBATCH + b) * TSEQ;

  const int tid  = threadIdx.x;
  const int w    = tid >> 6;        // wave id: q-row block
  const int lane = tid & 63;
  const int lr   = lane & 15;
  const int lg   = lane >> 4;

  __shared__ __align__(16) unsigned short Qs[64][72];
  __shared__ __align__(16) unsigned short Ks[64][72];          // [key][dim]
  __shared__ __align__(16) unsigned short Vs[64][72];          // [dim][key]
  __shared__ __align__(16) unsigned short Ps[4][16][72];       // per-wave P

  // stage Q once (scale 1/sqrt(64) folded in)
  #pragma unroll
  for (int it = 0; it < 4; ++it) {
    int idx = tid + it * 256;                  // 0..1023
    int r = idx >> 4, dq = (idx & 15) << 2;
    const float4 val = *(const float4*)&q[(rowbase + qt * 64 + r) * DMODEL + h * 64 + dq];
    unsigned short* dst = &Qs[r][dq];
    dst[0] = f2bf(val.x * 0.125f); dst[1] = f2bf(val.y * 0.125f);
    dst[2] = f2bf(val.z * 0.125f); dst[3] = f2bf(val.w * 0.125f);
  }

  f32x4 oacc[4] = {};
  float m[4], l[4];
  #pragma unroll
  for (int r = 0; r < 4; ++r) { m[r] = -1e30f; l[r] = 0.f; }

  for (int kt = 0; kt <= qt; ++kt) {
    __syncthreads();
    #pragma unroll
    for (int it = 0; it < 4; ++it) {
      int idx = tid + it * 256;
      int r = idx >> 4, dq = (idx & 15) << 2;
      size_t g = (rowbase + kt * 64 + r) * DMODEL + h * 64 + dq;
      const float4 kv = *(const float4*)&k[g];
      unsigned short* dk = &Ks[r][dq];
      dk[0] = f2bf(kv.x); dk[1] = f2bf(kv.y); dk[2] = f2bf(kv.z); dk[3] = f2bf(kv.w);
      const float4 vv = *(const float4*)&v[g];
      Vs[dq + 0][r] = f2bf(vv.x); Vs[dq + 1][r] = f2bf(vv.y);
      Vs[dq + 2][r] = f2bf(vv.z); Vs[dq + 3][r] = f2bf(vv.w);
    }
    __syncthreads();

    // ---- QK^T: s[j] = Q[w*16..][.] @ K[j*16..][.]^T
    f32x4 s[4] = {};
    #pragma unroll
    for (int c = 0; c < 2; ++c) {
      short8 a = *(const short8*)&Qs[w * 16 + lr][c * 32 + lg * 8];
      #pragma unroll
      for (int j = 0; j < 4; ++j) {
        short8 bb = *(const short8*)&Ks[j * 16 + lr][c * 32 + lg * 8];
        s[j] = __builtin_amdgcn_mfma_f32_16x16x32_bf16(a, bb, s[j], 0, 0, 0);
      }
    }

    // ---- causal mask (diagonal tile only; offsets equal so relative works)
    if (kt == qt) {
      #pragma unroll
      for (int j = 0; j < 4; ++j)
        #pragma unroll
        for (int r = 0; r < 4; ++r) {
          int row = w * 16 + lg * 4 + r;
          int col = j * 16 + lr;
          if (col > row) s[j][r] = -1e30f;
        }
    }

    // ---- online softmax stats (rows live in 16-lane groups)
    float mx[4], al[4];
    #pragma unroll
    for (int r = 0; r < 4; ++r)
      mx[r] = fmaxf(fmaxf(s[0][r], s[1][r]), fmaxf(s[2][r], s[3][r]));
    #pragma unroll
    for (int off = 1; off <= 8; off <<= 1)
      #pragma unroll
      for (int r = 0; r < 4; ++r)
        mx[r] = fmaxf(mx[r], __shfl_xor(mx[r], off));
    #pragma unroll
    for (int r = 0; r < 4; ++r) {
      float mn = fmaxf(m[r], mx[r]);
      al[r] = __expf(m[r] - mn);
      m[r] = mn;
    }
    float rs[4] = {0.f, 0.f, 0.f, 0.f};
    #pragma unroll
    for (int j = 0; j < 4; ++j)
      #pragma unroll
      for (int r = 0; r < 4; ++r) {
        float pe = __expf(s[j][r] - m[r]);
        s[j][r] = pe;
        rs[r] += pe;
      }
    #pragma unroll
    for (int off = 1; off <= 8; off <<= 1)
      #pragma unroll
      for (int r = 0; r < 4; ++r)
        rs[r] += __shfl_xor(rs[r], off);
    #pragma unroll
    for (int r = 0; r < 4; ++r) l[r] = l[r] * al[r] + rs[r];

    // ---- rescale O accumulator (same row mapping as stats)
    #pragma unroll
    for (int j = 0; j < 4; ++j)
      #pragma unroll
      for (int r = 0; r < 4; ++r)
        oacc[j][r] *= al[r];

    // ---- P: C/D layout -> A-operand layout via per-wave LDS (no barrier)
    #pragma unroll
    for (int j = 0; j < 4; ++j)
      #pragma unroll
      for (int r = 0; r < 4; ++r)
        Ps[w][lg * 4 + r][j * 16 + lr] = f2bf(s[j][r]);

    // ---- PV: oacc[j] += P @ V[., j*16..]
    #pragma unroll
    for (int c = 0; c < 2; ++c) {
      short8 a = *(const short8*)&Ps[w][lr][c * 32 + lg * 8];
      #pragma unroll
      for (int j = 0; j < 4; ++j) {
        short8 bb = *(const short8*)&Vs[j * 16 + lr][c * 32 + lg * 8];
        oacc[j] = __builtin_amdgcn_mfma_f32_16x16x32_bf16(a, bb, oacc[j], 0, 0, 0);
      }
    }
  }

  // ---- write out
  float inv[4];
  #pragma unroll
  for (int r = 0; r < 4; ++r) inv[r] = 1.f / l[r];
  #pragma unroll
  for (int j = 0; j < 4; ++j)
    #pragma unroll
    for (int r = 0; r < 4; ++r) {
      size_t row = rowbase + qt * 64 + w * 16 + lg * 4 + r;
      o[row * DMODEL + h * 64 + j * 16 + lr] = oacc[j][r] * inv[r];
    }
}

// ---------------------------------------------------------------------------
// LayerNorm over last dim (128), band-indexed scale/bias (band = row>>13).
// ---------------------------------------------------------------------------
struct LNA {
  const float* x;
  float* xn;
  const float* ls[7];
  const float* lb[7];
};

__global__ __launch_bounds__(256) void ln_kernel(LNA p) {
  const int tid = threadIdx.x;
  const int rr = tid >> 6, lane = tid & 63;
  const size_t row = (size_t)blockIdx.x * 4 + rr;
  const float* xp = p.x + row * DMODEL;
  float a = xp[lane], b = xp[lane + 64];
  float s = a + b;
  #pragma unroll
  for (int off = 32; off; off >>= 1) s += __shfl_xor(s, off);
  float mean = s * (1.f / 128.f);
  float da = a - mean, db = b - mean;
  float vs = da * da + db * db;
  #pragma unroll
  for (int off = 32; off; off >>= 1) vs += __shfl_xor(vs, off);
  float rstd = rsqrtf(vs * (1.f / 128.f) + 1e-5f);
  int band = (int)(row >> 13);
  const float* ls = p.ls[band];
  const float* lb = p.lb[band];
  float* op = p.xn + row * DMODEL;
  op[lane]      = da * rstd * ls[lane]      + lb[lane];
  op[lane + 64] = db * rstd * ls[lane + 64] + lb[lane + 64];
}

__global__ void bias6_kernel(const float* __restrict__ br_b, float* __restrict__ out) {
  int d = threadIdx.x;
  float s = 0.f;
  #pragma unroll
  for (int j = 0; j < 6; ++j) s += br_b[j * 128 + d];
  out[d] = s * (1.f / 6.f);
}

// ---------------------------------------------------------------------------
extern "C" void kernel_launch(void* const* d_in, const int* in_sizes, int n_in,
                              void* d_out, int out_size, void* d_ws, size_t ws_size,
                              hipStream_t stream) {
  bool dict = (in_sizes[2] != 896);
  const float* bands = (const float*)d_in[0];
  const float* Wq = (const float*)d_in[1];
  const float *Wk, *Wv, *Wo, *bq, *bk, *bv, *bo;
  if (dict) {
    Wk = (const float*)d_in[2]; Wv = (const float*)d_in[3]; Wo = (const float*)d_in[4];
    bq = (const float*)d_in[5]; bk = (const float*)d_in[6];
    bv = (const float*)d_in[7]; bo = (const float*)d_in[8];
  } else {
    bq = (const float*)d_in[2]; Wk = (const float*)d_in[3]; bk = (const float*)d_in[4];
    Wv = (const float*)d_in[5]; bv = (const float*)d_in[6];
    Wo = (const float*)d_in[7]; bo = (const float*)d_in[8];
  }
  const float* g_ls = (const float*)d_in[9];
  const float* g_lb = (const float*)d_in[10];
  const float* g_w1 = (const float*)d_in[11];
  const float* g_b1 = (const float*)d_in[12];
  const float* g_w2 = (const float*)d_in[13];
  const float* g_b2 = (const float*)d_in[14];
  const float* g_wg = (const float*)d_in[15];
  const float* g_bg = (const float*)d_in[16];
  const float* h_ls = (const float*)d_in[17];
  const float* h_lb = (const float*)d_in[18];
  const float* h_w1 = (const float*)d_in[19];
  const float* h_b1 = (const float*)d_in[20];
  const float* h_w2 = (const float*)d_in[21];
  const float* h_b2 = (const float*)d_in[22];
  const float* r_ls = (const float*)d_in[23];
  const float* r_lb = (const float*)d_in[24];
  const float* r_w1 = (const float*)d_in[25];
  const float* r_b1 = (const float*)d_in[26];
  const float* r_w2 = (const float*)d_in[27];
  const float* r_b2 = (const float*)d_in[28];
  const float* wp_w = (const float*)d_in[29];
  const float* wp_b = (const float*)d_in[30];
  const float* wg_w = (const float*)d_in[31];
  const float* wg_b = (const float*)d_in[32];
  const float* br_w = (const float*)d_in[33];
  const float* br_b = (const float*)d_in[34];
  const float* bg_w = (const float*)d_in[35];
  const float* bg_b = (const float*)d_in[36];
  float* out = (float*)d_out;

  const int hN[7] = {256, 256, 256, 384, 384, 512, 512};
  const float* lsP[7] = {g_ls, g_ls + 128, g_ls + 256, h_ls, h_ls + 128, r_ls, r_ls + 128};
  const float* lbP[7] = {g_lb, g_lb + 128, g_lb + 256, h_lb, h_lb + 128, r_lb, r_lb + 128};
  const float* w1p[7] = {g_w1, g_w1 + 32768, g_w1 + 65536,
                         h_w1, h_w1 + 49152, r_w1, r_w1 + 65536};
  const float* b1p[7] = {g_b1, g_b1 + 256, g_b1 + 512,
                         h_b1, h_b1 + 384, r_b1, r_b1 + 512};
  const float* w2p[7] = {g_w2, g_w2 + 32768, g_w2 + 65536,
                         h_w2, h_w2 + 49152, r_w2, r_w2 + 65536};
  const float* b2p[7] = {g_b2, g_b2 + 128, g_b2 + 256,
                         h_b2, h_b2 + 128, r_b2, r_b2 + 128};

  auto LP = [&](PArgs& p, int Z) {
    dim3 grid(MBAND / 64, p.N / 64, Z);
    gemm_b<<<grid, dim3(256), 0, stream>>>(p);
  };

  float* ws = (float*)d_ws;
  const size_t needFast = (36 * BANDE + 256) * sizeof(float);   // ~151 MB

  if (ws_size >= needFast) {
    // =================== FAST PATH: all bands batched ===================
    float* qb  = ws;                 // 7 BANDE   (later: x)
    float* kb  = qb + 7 * BANDE;     // 7 BANDE   (later: xn)
    float* vb  = kb + 7 * BANDE;     // 7 BANDE   (later: gate, 3 used)
    float* ob  = vb + 7 * BANDE;     // 7 BANDE   (later: y)
    float* hid = ob + 7 * BANDE;     // 8 BANDE   (later: info 6 + bridge 1)
    float* bbias = hid + 8 * BANDE;  // 128
    float* xb = qb;
    float* xnb = kb;
    float* gateb = vb;
    float* yb = ob;
    float* info = hid;
    float* bridge = hid + 6 * BANDE;

    // 1-3. Q/K/V projections, Z=7 each
    const float* Wqkv[3] = {Wq, Wk, Wv};
    const float* bqkv[3] = {bq, bk, bv};
    float* oqkv[3] = {qb, kb, vb};
    for (int w = 0; w < 3; ++w) {
      PArgs p{};
      p.A = bands; p.W = Wqkv[w]; p.bias = bqkv[w]; p.O = oqkv[w];
      for (int z = 0; z < 7; ++z) {
        p.Aoff[z] = z * BANDE; p.Woff[z] = (size_t)z * 16384;
        p.boff[z] = (size_t)z * 128; p.Ooff[z] = z * BANDE;
      }
      p.K = 128; p.N = 128; p.op = 0; p.alpha = 1.f;
      LP(p, 7);
    }

    // 4. attention, all bands
    attn_kernel<<<dim3(NBAND * 256), dim3(256), 0, stream>>>(qb, kb, vb, ob);

    // 5. x = bands + o @ Wo + bo  (-> qb region)
    {
      PArgs p{};
      p.A = ob; p.W = Wo; p.bias = bo; p.resid = bands; p.O = xb;
      for (int z = 0; z < 7; ++z) {
        p.Aoff[z] = z * BANDE; p.Woff[z] = (size_t)z * 16384;
        p.boff[z] = (size_t)z * 128; p.roff[z] = z * BANDE; p.Ooff[z] = z * BANDE;
      }
      p.K = 128; p.N = 128; p.op = 3; p.alpha = 1.f;
      LP(p, 7);
    }

    // 6. LN all bands
    {
      LNA p{};
      p.x = xb; p.xn = xnb;
      for (int n = 0; n < 7; ++n) { p.ls[n] = lsP[n]; p.lb[n] = lbP[n]; }
      ln_kernel<<<dim3(NBAND * MBAND / 4), dim3(256), 0, stream>>>(p);
    }

    // 7. geo gates, Z=3
    {
      PArgs p{};
      p.A = xb; p.W = g_wg; p.bias = g_bg; p.O = gateb;
      for (int z = 0; z < 3; ++z) {
        p.Aoff[z] = z * BANDE; p.Woff[z] = (size_t)z * 16384;
        p.boff[z] = (size_t)z * 128; p.Ooff[z] = z * BANDE;
      }
      p.K = 128; p.N = 128; p.op = 2; p.alpha = 1.f;
      LP(p, 3);
    }

    // 8-13. MLP per group: geo(3,256) hyb(2,384) rea(2,512)
    const int gcnt[3] = {3, 2, 2};
    const int gbase[3] = {0, 3, 5};
    for (int grp = 0; grp < 3; ++grp) {
      int cnt = gcnt[grp], base = gbase[grp], N1 = hN[base];
      size_t hstride = (size_t)MBAND * N1;
      {  // hidden = gelu(xn @ w1 + b1)
        PArgs p{};
        p.A = xnb; p.W = w1p[base]; p.bias = b1p[base]; p.O = hid;
        for (int z = 0; z < cnt; ++z) {
          p.Aoff[z] = (size_t)(base + z) * BANDE;
          p.Woff[z] = (size_t)(w1p[base + z] - w1p[base]);
          p.boff[z] = (size_t)(b1p[base + z] - b1p[base]);
          p.Ooff[z] = z * hstride;
        }
        p.K = 128; p.N = N1; p.op = 1; p.alpha = 1.f;
        LP(p, cnt);
      }
      {  // y = x + [gate]*(hid @ w2 + b2)
        PArgs p{};
        p.A = hid; p.W = w2p[base]; p.bias = b2p[base];
        p.resid = xb; p.O = yb;
        if (grp == 0) p.extra = gateb;
        for (int z = 0; z < cnt; ++z) {
          p.Aoff[z] = z * hstride;
          p.Woff[z] = (size_t)(w2p[base + z] - w2p[base]);
          p.boff[z] = (size_t)(b2p[base + z] - b2p[base]);
          p.roff[z] = (size_t)(base + z) * BANDE;
          p.eoff[z] = z * BANDE;
          p.Ooff[z] = (size_t)(base + z) * BANDE;
        }
        p.K = N1; p.N = 128; p.op = 5; p.alpha = 1.f;
        LP(p, cnt);
      }
    }

    // 14. info, Z=6
    {
      PArgs p{};
      p.A = yb; p.W = wp_w; p.bias = wp_b; p.O = info;
      for (int z = 0; z < 6; ++z) {
        int t = (z < 3) ? z : z + 1;
        int src = 6 - t;
        int i = (t < 3) ? t : 6 - t;
        p.Aoff[z] = (size_t)src * BANDE; p.Woff[z] = (size_t)i * 16384;
        p.boff[z] = (size_t)i * 128; p.Ooff[z] = (size_t)z * BANDE;
      }
      p.K = 128; p.N = 128; p.op = 0; p.alpha = 1.f;
      LP(p, 6);
    }

    // 15. final gates for 6 targets (2-part K)
    {
      PArgs p{};
      p.A = yb; p.W = wg_w; p.A2 = info; p.W2 = wg_w;
      p.bias = wg_b; p.resid = yb; p.extra = info; p.O = out;
      for (int z = 0; z < 6; ++z) {
        int t = (z < 3) ? z : z + 1;
        int i = (t < 3) ? t : 6 - t;
        p.Aoff[z] = (size_t)t * BANDE;  p.Woff[z] = (size_t)i * 32768;
        p.A2off[z] = (size_t)z * BANDE; p.W2off[z] = (size_t)i * 32768 + 16384;
        p.boff[z] = (size_t)i * 128;
        p.roff[z] = (size_t)t * BANDE;  p.eoff[z] = (size_t)z * BANDE;
        p.Ooff[z] = (size_t)t * BANDE;
      }
      p.K = 128; p.N = 128; p.op = 4; p.alpha = 1.f;
      LP(p, 6);
    }

    // 16-17. bridge
    bias6_kernel<<<dim3(1), dim3(128), 0, stream>>>(br_b, bbias);
    bridge_kernel<<<dim3(MBAND / 64, 2), dim3(256), 0, stream>>>(yb, br_w, bbias, bridge);

    // 18. band-3 final (2-part)
    {
      PArgs p{};
      p.A = yb; p.W = bg_w; p.A2 = bridge; p.W2 = bg_w;
      p.bias = bg_b; p.resid = yb; p.extra = bridge; p.O = out;
      p.Aoff[0] = 3 * BANDE; p.Woff[0] = 0;
      p.A2off[0] = 0; p.W2off[0] = 16384;
      p.boff[0] = 0; p.roff[0] = 3 * BANDE; p.eoff[0] = 0; p.Ooff[0] = 3 * BANDE;
      p.K = 128; p.N = 128; p.op = 4; p.alpha = 1.f;
      LP(p, 1);
    }
  } else {
    // =================== FALLBACK: per-band (63 MB) ===================
    float* yb   = ws;                         // 7 BANDE
    float* sq   = yb + 7 * BANDE;
    float* sk   = sq + BANDE;
    float* sv   = sk + BANDE;
    float* so   = sv + BANDE;
    float* shid = so + BANDE;                 // 4 BANDE
    float* bbias = shid + 4 * BANDE;          // 128

    for (int n = 0; n < NBAND; ++n) {
      const float* bn = bands + (size_t)n * BANDE;
      const float* W3[3] = {Wq + n * 16384, Wk + n * 16384, Wv + n * 16384};
      const float* b3[3] = {bq + n * 128, bk + n * 128, bv + n * 128};
      float* o3[3] = {sq, sk, sv};
      for (int w = 0; w < 3; ++w) {
        PArgs p{};
        p.A = bn; p.W = W3[w]; p.bias = b3[w]; p.O = o3[w];
        p.K = 128; p.N = 128; p.op = 0; p.alpha = 1.f;
        LP(p, 1);
      }
      attn_kernel<<<dim3(256), dim3(256), 0, stream>>>(sq, sk, sv, so);
      {
        PArgs p{};
        p.A = so; p.W = Wo + n * 16384; p.bias = bo + n * 128;
        p.resid = bn; p.O = sq;
        p.K = 128; p.N = 128; p.op = 3; p.alpha = 1.f;
        LP(p, 1);
      }
      {
        LNA p{};
        p.x = sq; p.xn = sk; p.ls[0] = lsP[n]; p.lb[0] = lbP[n];
        ln_kernel<<<dim3(MBAND / 4), dim3(256), 0, stream>>>(p);
      }
      if (n < 3) {
        PArgs p{};
        p.A = sq; p.W = g_wg + n * 16384; p.bias = g_bg + n * 128; p.O = sv;
        p.K = 128; p.N = 128; p.op = 2; p.alpha = 1.f;
        LP(p, 1);
      }
      {
        PArgs p{};
        p.A = sk; p.W = w1p[n]; p.bias = b1p[n]; p.O = shid;
        p.K = 128; p.N = hN[n]; p.op = 1; p.alpha = 1.f;
        LP(p, 1);
      }
      {
        PArgs p{};
        p.A = shid; p.W = w2p[n]; p.bias = b2p[n];
        p.resid = sq; p.O = yb; p.Ooff[0] = (size_t)n * BANDE;
        if (n < 3) p.extra = sv;
        p.K = hN[n]; p.N = 128; p.op = 5; p.alpha = 1.f;
        LP(p, 1);
      }
    }

    for (int s = 0; s < 6; ++s) {
      int t = (s < 3) ? s : s + 1;
      int i = (t < 3) ? t : 6 - t;
      int src = 6 - t;
      {
        PArgs p{};
        p.A = yb; p.Aoff[0] = (size_t)src * BANDE;
        p.W = wp_w; p.Woff[0] = (size_t)i * 16384;
        p.bias = wp_b; p.boff[0] = (size_t)i * 128;
        p.O = sq;
        p.K = 128; p.N = 128; p.op = 0; p.alpha = 1.f;
        LP(p, 1);
      }
      {
        PArgs p{};
        p.A = yb; p.Aoff[0] = (size_t)t * BANDE;
        p.W = wg_w; p.Woff[0] = (size_t)i * 32768;
        p.A2 = sq; p.W2 = wg_w; p.W2off[0] = (size_t)i * 32768 + 16384;
        p.bias = wg_b; p.boff[0] = (size_t)i * 128;
        p.resid = yb; p.roff[0] = (size_t)t * BANDE;
        p.extra = sq; p.O = out; p.Ooff[0] = (size_t)t * BANDE;
        p.K = 128; p.N = 128; p.op = 4; p.alpha = 1.f;
        LP(p, 1);
      }
    }

    bias6_kernel<<<dim3(1), dim3(128), 0, stream>>>(br_b, bbias);
    bridge_kernel<<<dim3(MBAND / 64, 2), dim3(256), 0, stream>>>(yb, br_w, bbias, sk);
    {
      PArgs p{};
      p.A = yb; p.Aoff[0] = 3 * BANDE; p.W = bg_w;
      p.A2 = sk; p.W2 = bg_w; p.W2off[0] = 16384;
      p.bias = bg_b; p.resid = yb; p.roff[0] = 3 * BANDE;
      p.extra = sk; p.O = out; p.Ooff[0] = 3 * BANDE;
      p.K = 128; p.N = 128; p.op = 4; p.alpha = 1.f;
      LP(p, 1);
    }
  }
}